// Round 7
// baseline (636.658 us; speedup 1.0000x reference)
//
#include <hip/hip_runtime.h>
#include <hip/hip_bf16.h>

// Problem constants (fixed by the reference)
#define B_ 8
#define C_ 256
#define E_ 512
#define T_ 8192
#define K_ 512
#define CT_ (C_*T_)
#define CAP_ 32768          // candidate capacity per batch (expected ~4100)
#define SUBS_ 64            // t-subsample stride
#define SCOLS_ (T_/SUBS_)   // 128
#define SUBN_ (E_*SCOLS_)   // 65536 subsample points per batch
#define RANK_ 64            // subsample rank -> expected full count ~4096
#define NB1_ 4096           // subsample histogram bins over [-1,1)
#define NB2_ 4096           // selection histogram bins over [0,0.5)

typedef __attribute__((ext_vector_type(8))) short bf16x8;
typedef __attribute__((ext_vector_type(4))) float f32x4;

__device__ __forceinline__ ushort f2bf(float f) {
    __hip_bfloat16 h = __float2bfloat16(f);
    return *reinterpret_cast<ushort*>(&h);
}
__device__ __forceinline__ float bf2f(ushort u) {
    __hip_bfloat16 h = *reinterpret_cast<__hip_bfloat16*>(&u);
    return __bfloat162float(h);
}

// async global->LDS, 16B per lane; LDS dest = wave-uniform base + lane*16,
// global source address is per-lane (we pass base; lane*16B added via gsrc).
__device__ __forceinline__ void gl16(const void* g, void* l) {
    __builtin_amdgcn_global_load_lds(
        (const __attribute__((address_space(1))) void*)g,
        (__attribute__((address_space(3))) void*)l, 16, 0, 0);
}

// Tiled operand layout (ushort units):
//   W tiles:  [etile(8)][cc(4)][cb(8)][erow(64)][8]   (16384 per etile)
//   X tiles:  [b*128+ttile][cc(4)][cb(8)][trow(64)][8] (16384 per ttile)
// One gl16 instruction = one [cb] block = 64 rows x 16B, contiguous 1KB.

// rn[b,t] = 1/(||x[b,:,t]|| + 1e-8); nrm = ||x|| + 1e-8; block 0 inits Z, cnt
__global__ void k_rn(const float* __restrict__ x, float* __restrict__ rn,
                     float* __restrict__ nrm, float* __restrict__ Z,
                     int* __restrict__ cnt) {
    if (blockIdx.x == 0 && threadIdx.x < B_) {
        Z[threadIdx.x] = 0.f; cnt[threadIdx.x] = 0;
    }
    int gid = blockIdx.x * 256 + threadIdx.x;   // B*T threads
    int b = gid / T_, t = gid % T_;
    const float* xp = x + (size_t)b * CT_ + t;
    float s0 = 0.f, s1 = 0.f, s2 = 0.f, s3 = 0.f;
    for (int c = 0; c < C_; c += 4) {
        float a0 = xp[(size_t)c * T_];
        float a1 = xp[(size_t)(c + 1) * T_];
        float a2 = xp[(size_t)(c + 2) * T_];
        float a3 = xp[(size_t)(c + 3) * T_];
        s0 += a0 * a0; s1 += a1 * a1; s2 += a2 * a2; s3 += a3 * a3;
    }
    float s = (s0 + s1) + (s2 + s3);
    float n = sqrtf(s) + 1e-8f;
    nrm[gid] = n;
    rn[gid] = 1.0f / n;
}

// split mask_w into bf16 hi/lo, TILED layout (coalesced 16B writes)
__global__ void k_split_w(const float* __restrict__ mw, ushort* __restrict__ mwh,
                          ushort* __restrict__ mwl) {
    int idx = blockIdx.x * 256 + threadIdx.x;   // E*C/8 = 16384 threads
    int erow = idx & 63;
    int cb = (idx >> 6) & 7;
    int cc = (idx >> 9) & 3;
    int etile = idx >> 11;
    int e = etile * 64 + erow;
    int c0 = cc * 64 + cb * 8;
    const float* src = mw + (size_t)e * C_ + c0;
    ushort4 h0, l0, h1, l1;
    float v;
    v = src[0]; h0.x = f2bf(v); l0.x = f2bf(v - bf2f(h0.x));
    v = src[1]; h0.y = f2bf(v); l0.y = f2bf(v - bf2f(h0.y));
    v = src[2]; h0.z = f2bf(v); l0.z = f2bf(v - bf2f(h0.z));
    v = src[3]; h0.w = f2bf(v); l0.w = f2bf(v - bf2f(h0.w));
    v = src[4]; h1.x = f2bf(v); l1.x = f2bf(v - bf2f(h1.x));
    v = src[5]; h1.y = f2bf(v); l1.y = f2bf(v - bf2f(h1.y));
    v = src[6]; h1.z = f2bf(v); l1.z = f2bf(v - bf2f(h1.z));
    v = src[7]; h1.w = f2bf(v); l1.w = f2bf(v - bf2f(h1.w));
    *(ushort4*)(mwh + (size_t)idx * 8) = h0;
    *(ushort4*)(mwh + (size_t)idx * 8 + 4) = h1;
    *(ushort4*)(mwl + (size_t)idx * 8) = l0;
    *(ushort4*)(mwl + (size_t)idx * 8 + 4) = l1;
}

// transpose + rn-scale + split into TILED layout:
// xh/xl[(b*128+ttile)*4+cc][cb][trow][8] = bf16split(x[b][c][t]*rn[b][t])
__launch_bounds__(256)
__global__ void k_split_x(const float* __restrict__ x, const float* __restrict__ rn,
                          ushort* __restrict__ xh, ushort* __restrict__ xl) {
    __shared__ float tile[64][76];
    __shared__ float rnv[64];
    int tid = threadIdx.x;
    int ttile = blockIdx.x, cc = blockIdx.y, b = blockIdx.z;
    int t0 = ttile * 64, c0 = cc * 64;
    if (tid < 64) rnv[tid] = rn[b * T_ + t0 + tid];
    const float* xb = x + (size_t)b * CT_;
#pragma unroll
    for (int q = 0; q < 4; ++q) {
        int idx = tid + q * 256;
        int cr = idx >> 4, t4 = (idx & 15) * 4;
        float4 v = *(const float4*)(xb + (size_t)(c0 + cr) * T_ + t0 + t4);
        *(float4*)&tile[cr][t4] = v;
    }
    __syncthreads();
    size_t obase = (((size_t)b * 128 + ttile) * 4 + cc) * 4096;
#pragma unroll
    for (int q = 0; q < 4; ++q) {
        int idx = tid + q * 256;
        int tr = idx >> 4, c4 = (idx & 15) * 4;
        float s = rnv[tr];
        float v0 = tile[c4 + 0][tr] * s;
        float v1 = tile[c4 + 1][tr] * s;
        float v2 = tile[c4 + 2][tr] * s;
        float v3 = tile[c4 + 3][tr] * s;
        ushort4 h, l;
        h.x = f2bf(v0); l.x = f2bf(v0 - bf2f(h.x));
        h.y = f2bf(v1); l.y = f2bf(v1 - bf2f(h.y));
        h.z = f2bf(v2); l.z = f2bf(v2 - bf2f(h.z));
        h.w = f2bf(v3); l.w = f2bf(v3 - bf2f(h.w));
        int cb = c4 >> 3, half = (c4 >> 2) & 1;
        size_t ro = obase + (size_t)cb * 512 + tr * 8 + half * 4;
        *(ushort4*)(xh + ro) = h;
        *(ushort4*)(xl + ro) = l;
    }
}

// gather subsampled, rn-scaled x: xs[b][c][s] = x[b][c][s*64] * rn[b][s*64]
__global__ void k_gather(const float* __restrict__ x, const float* __restrict__ rn,
                         float* __restrict__ xs) {
    int gid = blockIdx.x * 256 + threadIdx.x;   // B*C*SCOLS threads = 262144
    int s = gid & (SCOLS_ - 1);
    int c = (gid >> 7) & (C_ - 1);
    int b = gid >> 15;
    int t = s * SUBS_;
    xs[gid] = x[(size_t)b * CT_ + (size_t)c * T_ + t] * rn[b * T_ + t];
}

// tiled f32 GEMM on compact gathered buffer (small: ~270 MFLOP)
__launch_bounds__(256)
__global__ void k_msub2(const float* __restrict__ xs, const float* __restrict__ mw,
                        const float* __restrict__ mb, float* __restrict__ msub) {
    __shared__ float As[64][68];
    __shared__ float Bs[64][68];
    int tid = threadIdx.x;
    int tx = tid & 15, ty = tid >> 4;
    int s0 = blockIdx.x * 64, e0 = blockIdx.y * 64, b = blockIdx.z;
    const float* xb = xs + (size_t)b * C_ * SCOLS_;
    float acc[4][4] = {};
    for (int c0 = 0; c0 < C_; c0 += 64) {
#pragma unroll
        for (int r = 0; r < 4; ++r) {
            int i = (tid >> 4) + r * 16;
            int kq = (tid & 15) * 4;
            float4 av = *(const float4*)(mw + (size_t)(e0 + i) * C_ + c0 + kq);
            As[kq + 0][i] = av.x; As[kq + 1][i] = av.y;
            As[kq + 2][i] = av.z; As[kq + 3][i] = av.w;
        }
#pragma unroll
        for (int r = 0; r < 4; ++r) {
            int k = (tid >> 4) + r * 16;
            int jq = (tid & 15) * 4;
            *(float4*)(&Bs[k][jq]) =
                *(const float4*)(xb + (size_t)(c0 + k) * SCOLS_ + s0 + jq);
        }
        __syncthreads();
#pragma unroll
        for (int k = 0; k < 64; ++k) {
            float4 a = *(const float4*)(&As[k][ty * 4]);
            float4 bq = *(const float4*)(&Bs[k][tx * 4]);
            float av[4] = {a.x, a.y, a.z, a.w};
            float bv[4] = {bq.x, bq.y, bq.z, bq.w};
#pragma unroll
            for (int ii = 0; ii < 4; ++ii)
#pragma unroll
                for (int jj = 0; jj < 4; ++jj)
                    acc[ii][jj] += av[ii] * bv[jj];
        }
        __syncthreads();
    }
#pragma unroll
    for (int ii = 0; ii < 4; ++ii) {
        float mbv = mb[e0 + ty * 4 + ii];
#pragma unroll
        for (int jj = 0; jj < 4; ++jj) {
            int e = e0 + ty * 4 + ii, s = s0 + tx * 4 + jj;
            msub[(size_t)b * SUBN_ + e * SCOLS_ + s] = acc[ii][jj] + mbv;
        }
    }
}

// per-batch conservative threshold tau0 from subsample rank-64
__global__ void k_tau(const float* __restrict__ msub, float* __restrict__ tau0) {
    __shared__ int h[NB1_];
    __shared__ int part[256];
    int b = blockIdx.x, tid = threadIdx.x;
    for (int i = tid; i < NB1_; i += 256) h[i] = 0;
    __syncthreads();
    const float* mp = msub + b * SUBN_;
    for (int j = tid; j < SUBN_; j += 256) {
        float v = mp[j];
        int bin = (int)((v + 1.0f) * ((float)NB1_ * 0.5f));
        bin = bin < 0 ? 0 : (bin > NB1_ - 1 ? NB1_ - 1 : bin);
        atomicAdd(&h[bin], 1);
    }
    __syncthreads();
    int ps = 0;
    for (int j = 0; j < 16; ++j) ps += h[tid * 16 + j];
    part[tid] = ps;
    __syncthreads();
    if (tid == 0) {
        int cum = 0, bf = 0;
        for (int i = 255; i >= 0; --i) {
            if (cum + part[i] >= RANK_) {
                int cum2 = cum;
                for (int j = 15; j >= 0; --j) {
                    cum2 += h[i * 16 + j];
                    if (cum2 >= RANK_) { bf = i * 16 + j; break; }
                }
                break;
            }
            cum += part[i];
        }
        tau0[b] = (float)bf * (2.0f / (float)NB1_) - 1.0f;  // bin lower edge
    }
}

// ---------------- fast main GEMM: tiled operands, XCD-grouped ----------------
// R5-proven structure (gl16 -> barrier -> MFMA -> barrier per chunk); operands
// pre-tiled so every gl16 reads a contiguous 1KB (full coalescing) and every
// ds_read_b128 fragment is conflict-free ([cb16][row] LDS layout, no XOR).
__launch_bounds__(256)
__global__ void k_gemmf(const ushort* __restrict__ mwh, const ushort* __restrict__ mwl,
                        const ushort* __restrict__ xh, const ushort* __restrict__ xl,
                        const float* __restrict__ mb, const float* __restrict__ tau0,
                        float* __restrict__ Z, int* __restrict__ cnt,
                        float* __restrict__ cval, int* __restrict__ cidx) {
    __shared__ ushort S[4][4096];   // Ah, Al, Bh, Bl as [cb(8)][row(64)][8]
    __shared__ float red[4];
    int tid = threadIdx.x, lane = tid & 63, w = tid >> 6;
    int f = blockIdx.x;
    int xcd = f & 7, slot = f >> 3;          // XCD round-robin grouping
    int xtile = xcd * 128 + (slot >> 3);     // 0..1023 = b*128 + t-tile
    int e0 = (slot & 7) * 64;                // e-block fastest within XCD
    int b = xtile >> 7;
    int t0 = (xtile & 127) * 64;

    const ushort* gbase;
    if (w == 0)      gbase = mwh + (size_t)(e0 >> 6) * 16384;
    else if (w == 1) gbase = mwl + (size_t)(e0 >> 6) * 16384;
    else if (w == 2) gbase = xh + ((size_t)b * 128 + (t0 >> 6)) * 16384;
    else             gbase = xl + ((size_t)b * 128 + (t0 >> 6)) * 16384;
    const ushort* gsrc = gbase + lane * 8;   // lane-contiguous 16B
    ushort* lbase = &S[w][0];

    f32x4 acc[4] = {{0.f,0.f,0.f,0.f},{0.f,0.f,0.f,0.f},
                    {0.f,0.f,0.f,0.f},{0.f,0.f,0.f,0.f}};
    int a15 = lane & 15;
    int arow = w * 16 + a15;
    int khalf = lane >> 4;                    // 0..3

    for (int cc = 0; cc < 4; ++cc) {
#pragma unroll
        for (int i = 0; i < 8; ++i)
            gl16(gsrc + (size_t)(cc * 8 + i) * 512, lbase + i * 512);
        __syncthreads();
#pragma unroll
        for (int ks = 0; ks < 2; ++ks) {
            int cb16 = ks * 4 + khalf;
            int aoff = (cb16 * 64 + arow) * 16;
            bf16x8 ah = *(const bf16x8*)((const char*)&S[0][0] + aoff);
            bf16x8 al = *(const bf16x8*)((const char*)&S[1][0] + aoff);
#pragma unroll
            for (int n = 0; n < 4; ++n) {
                int brow = n * 16 + a15;
                int boff = (cb16 * 64 + brow) * 16;
                bf16x8 bh = *(const bf16x8*)((const char*)&S[2][0] + boff);
                bf16x8 bl = *(const bf16x8*)((const char*)&S[3][0] + boff);
                acc[n] = __builtin_amdgcn_mfma_f32_16x16x32_bf16(ah, bh, acc[n], 0, 0, 0);
                acc[n] = __builtin_amdgcn_mfma_f32_16x16x32_bf16(ah, bl, acc[n], 0, 0, 0);
                acc[n] = __builtin_amdgcn_mfma_f32_16x16x32_bf16(al, bh, acc[n], 0, 0, 0);
            }
        }
        __syncthreads();
    }
    // epilogue: C/D layout col(t)=lane&15, row(e)=(lane>>4)*4+reg
    float tau = tau0[b];
    float zs = 0.f;
    float mbv[4];
#pragma unroll
    for (int r = 0; r < 4; ++r) mbv[r] = mb[e0 + w * 16 + (lane >> 4) * 4 + r];
#pragma unroll
    for (int n = 0; n < 4; ++n) {
        int t = t0 + n * 16 + a15;
#pragma unroll
        for (int r = 0; r < 4; ++r) {
            int e = e0 + w * 16 + (lane >> 4) * 4 + r;
            float v = acc[n][r] + mbv[r];
            zs += __expf(v);
            if (v >= tau) {
                int pos = atomicAdd(&cnt[b], 1);
                if (pos < CAP_) {
                    cval[b * CAP_ + pos] = v;
                    cidx[b * CAP_ + pos] = e * T_ + t;
                }
            }
        }
    }
#pragma unroll
    for (int off = 32; off; off >>= 1) zs += __shfl_xor(zs, off, 64);
    if (lane == 0) red[w] = zs;
    __syncthreads();
    if (tid == 0) atomicAdd(&Z[b], (red[0] + red[1]) + (red[2] + red[3]));
}

// ---------------- fallback main GEMM (R2-proven, used if ws too small) ------
#define PADC 88
__launch_bounds__(256)
__global__ void k_gemm(const float* __restrict__ x, const float* __restrict__ mw,
                       const float* __restrict__ mb, const float* __restrict__ rn,
                       const float* __restrict__ tau0, float* __restrict__ Z,
                       int* __restrict__ cnt, float* __restrict__ cval,
                       int* __restrict__ cidx) {
    __shared__ ushort Ah[64][PADC], Al[64][PADC];
    __shared__ ushort Bh[64][PADC], Bl[64][PADC];
    __shared__ float red[4];
    int tid = threadIdx.x;
    int lane = tid & 63, w = tid >> 6;
    int t0 = blockIdx.x * 64, e0 = blockIdx.y * 64, b = blockIdx.z;
    const float* xb = x + (size_t)b * CT_;
    f32x4 acc[4] = {{0.f,0.f,0.f,0.f},{0.f,0.f,0.f,0.f},
                    {0.f,0.f,0.f,0.f},{0.f,0.f,0.f,0.f}};
    int arow = w * 16 + (lane & 15);
    int koff = (lane >> 4) * 8;

    for (int cc0 = 0; cc0 < C_; cc0 += 64) {
#pragma unroll
        for (int q = 0; q < 4; ++q) {
            int idx = tid + q * 256;
            int er = idx >> 4, c4 = (idx & 15) * 4;
            float4 v = *(const float4*)(mw + (size_t)(e0 + er) * C_ + cc0 + c4);
            ushort4 h, l;
            h.x = f2bf(v.x); l.x = f2bf(v.x - bf2f(h.x));
            h.y = f2bf(v.y); l.y = f2bf(v.y - bf2f(h.y));
            h.z = f2bf(v.z); l.z = f2bf(v.z - bf2f(h.z));
            h.w = f2bf(v.w); l.w = f2bf(v.w - bf2f(h.w));
            *(ushort4*)&Ah[er][c4] = h;
            *(ushort4*)&Al[er][c4] = l;
        }
#pragma unroll
        for (int q = 0; q < 4; ++q) {
            int idx = tid + q * 256;
            int cr = idx >> 4, t4 = (idx & 15) * 4;
            float4 v = *(const float4*)(xb + (size_t)(cc0 + cr) * T_ + t0 + t4);
            float vv[4] = {v.x, v.y, v.z, v.w};
#pragma unroll
            for (int j = 0; j < 4; ++j) {
                ushort h = f2bf(vv[j]);
                Bh[t4 + j][cr] = h;
                Bl[t4 + j][cr] = f2bf(vv[j] - bf2f(h));
            }
        }
        __syncthreads();
#pragma unroll
        for (int ks = 0; ks < 2; ++ks) {
            int cb = ks * 32 + koff;
            bf16x8 ah = *(const bf16x8*)&Ah[arow][cb];
            bf16x8 al = *(const bf16x8*)&Al[arow][cb];
#pragma unroll
            for (int n = 0; n < 4; ++n) {
                int brow = n * 16 + (lane & 15);
                bf16x8 bh = *(const bf16x8*)&Bh[brow][cb];
                bf16x8 bl = *(const bf16x8*)&Bl[brow][cb];
                acc[n] = __builtin_amdgcn_mfma_f32_16x16x32_bf16(ah, bh, acc[n], 0, 0, 0);
                acc[n] = __builtin_amdgcn_mfma_f32_16x16x32_bf16(ah, bl, acc[n], 0, 0, 0);
                acc[n] = __builtin_amdgcn_mfma_f32_16x16x32_bf16(al, bh, acc[n], 0, 0, 0);
            }
        }
        __syncthreads();
    }
    float tau = tau0[b];
    float zs = 0.f;
#pragma unroll
    for (int n = 0; n < 4; ++n) {
        int t = t0 + n * 16 + (lane & 15);
        float rnv = rn[b * T_ + t];
#pragma unroll
        for (int r = 0; r < 4; ++r) {
            int e = e0 + w * 16 + (lane >> 4) * 4 + r;
            float v = acc[n][r] * rnv + mb[e];
            zs += __expf(v);
            if (v >= tau) {
                int pos = atomicAdd(&cnt[b], 1);
                if (pos < CAP_) {
                    cval[b * CAP_ + pos] = v;
                    cidx[b * CAP_ + pos] = e * T_ + t;
                }
            }
        }
    }
#pragma unroll
    for (int off = 32; off; off >>= 1) zs += __shfl_xor(zs, off, 64);
    if (lane == 0) red[w] = zs;
    __syncthreads();
    if (tid == 0) atomicAdd(&Z[b], (red[0] + red[1]) + (red[2] + red[3]));
}

// exact top-K selection among candidates (value desc, index asc on ties)
__launch_bounds__(256)
__global__ void k_select(const float* __restrict__ cval, const int* __restrict__ cidx,
                         const int* __restrict__ cnt, const float* __restrict__ Z,
                         int* __restrict__ sel_e, int* __restrict__ sel_t,
                         float* __restrict__ sel_sp) {
    __shared__ int h[NB2_];
    __shared__ int part[256];
    __shared__ float bl_v[1024];
    __shared__ int bl_i[1024];
    __shared__ int nb, bstar, nabove, outcnt;
    int b = blockIdx.x, tid = threadIdx.x;
    int n = cnt[b]; if (n > CAP_) n = CAP_;
    for (int i = tid; i < NB2_; i += 256) h[i] = 0;
    if (tid == 0) { nb = 0; outcnt = 0; }
    __syncthreads();
    const float* vp = cval + b * CAP_;
    const int* ip = cidx + b * CAP_;
    for (int j = tid; j < n; j += 256) {
        int bin = (int)(vp[j] * ((float)NB2_ * 2.0f));   // [0,0.5) range
        bin = bin < 0 ? 0 : (bin > NB2_ - 1 ? NB2_ - 1 : bin);
        atomicAdd(&h[bin], 1);
    }
    __syncthreads();
    int ps = 0;
    for (int j = 0; j < 16; ++j) ps += h[tid * 16 + j];
    part[tid] = ps;
    __syncthreads();
    if (tid == 0) {
        int cum = 0, bs = 0, na = 0;
        for (int i = 255; i >= 0; --i) {
            if (cum + part[i] >= K_) {
                int cum2 = cum;
                for (int j = 15; j >= 0; --j) {
                    cum2 += h[i * 16 + j];
                    if (cum2 >= K_) { bs = i * 16 + j; na = cum2 - h[i * 16 + j]; break; }
                }
                break;
            }
            cum += part[i];
        }
        bstar = bs; nabove = na;
    }
    __syncthreads();
    int bs = bstar;
    for (int j = tid; j < n; j += 256) {
        float v = vp[j];
        int bin = (int)(v * ((float)NB2_ * 2.0f));
        bin = bin < 0 ? 0 : (bin > NB2_ - 1 ? NB2_ - 1 : bin);
        if (bin == bs) {
            int q = atomicAdd(&nb, 1);
            if (q < 1024) { bl_v[q] = v; bl_i[q] = ip[j]; }
        }
    }
    __syncthreads();
    float rZ = 1.0f / Z[b];
    for (int j = tid; j < n; j += 256) {
        float v = vp[j];
        int bin = (int)(v * ((float)NB2_ * 2.0f));
        bin = bin < 0 ? 0 : (bin > NB2_ - 1 ? NB2_ - 1 : bin);
        if (bin > bs) {
            int q = atomicAdd(&outcnt, 1);
            int idx = ip[j];
            sel_e[b * K_ + q] = idx / T_;
            sel_t[b * K_ + q] = idx % T_;
            sel_sp[b * K_ + q] = __expf(v) * rZ;
        }
    }
    __syncthreads();
    if (tid == 0) {
        int m = nb; if (m > 1024) m = 1024;
        for (int i = 1; i < m; ++i) {          // insertion sort: val desc, idx asc
            float v = bl_v[i]; int id = bl_i[i]; int j = i - 1;
            while (j >= 0 && (bl_v[j] < v || (bl_v[j] == v && bl_i[j] > id))) {
                bl_v[j + 1] = bl_v[j]; bl_i[j + 1] = bl_i[j]; --j;
            }
            bl_v[j + 1] = v; bl_i[j + 1] = id;
        }
        int need = K_ - nabove;
        for (int q = 0; q < need; ++q) {
            int slot = nabove + q;
            if (q < m) {
                int idx = bl_i[q];
                sel_e[b * K_ + slot] = idx / T_;
                sel_t[b * K_ + slot] = idx % T_;
                sel_sp[b * K_ + slot] = __expf(bl_v[q]) * rZ;
            } else {  // pathological fallback: harmless zero entries
                sel_e[b * K_ + slot] = 0; sel_t[b * K_ + slot] = 0;
                sel_sp[b * K_ + slot] = 0.f;
            }
        }
    }
}

// up at selected positions via tiled split-x:
// up = (sum_c uw[c]*(xh+xl)[t][c]) * nrm[t];  g = sp * (up + up_b)
__global__ void k_upg2(const ushort* __restrict__ xh, const ushort* __restrict__ xl,
                       const float* __restrict__ nrm, const float* __restrict__ uw,
                       const float* __restrict__ ub, const int* __restrict__ sel_e,
                       const int* __restrict__ sel_t, const float* __restrict__ sel_sp,
                       float* __restrict__ gval) {
    int gid = blockIdx.x * 256 + threadIdx.x;   // B*K waves
    int w = gid >> 6, lane = gid & 63;
    int b = w >> 9, i = w & (K_ - 1);
    int e = sel_e[b * K_ + i], t = sel_t[b * K_ + i];
    int ttile = t >> 6, trow = t & 63;
    int cc = lane >> 4, cb = (lane >> 1) & 7, half = lane & 1;
    size_t ro = ((((size_t)b * 128 + ttile) * 4 + cc) * 8 + cb) * 512
              + (size_t)trow * 8 + half * 4;          // c = lane*4 .. +4
    ushort4 h = *(const ushort4*)(xh + ro);
    ushort4 l = *(const ushort4*)(xl + ro);
    float4 wv = *(const float4*)(uw + (size_t)e * C_ + lane * 4);
    float acc = (bf2f(h.x) + bf2f(l.x)) * wv.x + (bf2f(h.y) + bf2f(l.y)) * wv.y
              + (bf2f(h.z) + bf2f(l.z)) * wv.z + (bf2f(h.w) + bf2f(l.w)) * wv.w;
#pragma unroll
    for (int off = 32; off; off >>= 1) acc += __shfl_down(acc, off, 64);
    if (lane == 0)
        gval[b * K_ + i] = sel_sp[b * K_ + i] * (acc * nrm[b * T_ + t] + ub[e]);
}

// fallback k_upg (raw x, strided)
__global__ void k_upg(const float* __restrict__ x, const float* __restrict__ uw,
                      const float* __restrict__ ub, const int* __restrict__ sel_e,
                      const int* __restrict__ sel_t, const float* __restrict__ sel_sp,
                      float* __restrict__ gval) {
    int gid = blockIdx.x * 256 + threadIdx.x;   // B*K waves
    int w = gid >> 6, lane = gid & 63;
    int b = w >> 9, i = w & (K_ - 1);
    int e = sel_e[b * K_ + i], t = sel_t[b * K_ + i];
    const float* xp = x + (size_t)b * CT_ + t;
    const float* wp = uw + (size_t)e * C_;
    float acc = 0.f;
    for (int c = lane; c < C_; c += 64) acc += wp[c] * xp[(size_t)c * T_];
    for (int off = 32; off; off >>= 1) acc += __shfl_down(acc, off, 64);
    if (lane == 0) gval[b * K_ + i] = sel_sp[b * K_ + i] * (acc + ub[e]);
}

// merged base + S1/Q: one wave per (b,c)
__global__ void k_bsq(const float* __restrict__ sw, const float* __restrict__ sb,
                      const float* __restrict__ db, const float* __restrict__ dw,
                      const int* __restrict__ sel_e, const float* __restrict__ gval,
                      float* __restrict__ base, float* __restrict__ S1,
                      float* __restrict__ Qv) {
    int wg = blockIdx.x * 4 + (threadIdx.x >> 6);   // 2048 waves
    int lane = threadIdx.x & 63;
    int b = wg >> 8, c = wg & (C_ - 1);
    float p = 0.f, s = 0.f, q = 0.f;
    for (int i = lane; i < K_; i += 64) {
        int e = sel_e[b * K_ + i];
        float g = gval[b * K_ + i];
        p += g * sw[(size_t)c * E_ + e];
        float wv = dw[(size_t)c * E_ + e] * g;
        s += wv; q += wv * wv;
    }
#pragma unroll
    for (int off = 32; off; off >>= 1) {
        p += __shfl_xor(p, off, 64);
        s += __shfl_xor(s, off, 64);
        q += __shfl_xor(q, off, 64);
    }
    if (lane == 0) {
        base[b * C_ + c] = p + sb[c] + db[c];
        S1[b * C_ + c] = s; Qv[b * C_ + c] = q;
    }
}

// BN stats analytic: mean/var per channel, then scale + per-(b,c) output base
__global__ void k_bnstats(const float* __restrict__ base, const float* __restrict__ S1,
                          const float* __restrict__ Qv, const float* __restrict__ bnw,
                          const float* __restrict__ bnb, float* __restrict__ scalec,
                          float* __restrict__ obase) {
    int c = threadIdx.x;
    float msum = 0.f;
    for (int b = 0; b < B_; ++b) msum += (float)T_ * base[b * C_ + c] + S1[b * C_ + c];
    float mean = msum / (float)(B_ * T_);
    float vs = 0.f;
    for (int b = 0; b < B_; ++b) {
        float d = base[b * C_ + c] - mean;
        vs += (float)T_ * d * d + 2.0f * d * S1[b * C_ + c] + Qv[b * C_ + c];
    }
    float var = vs / (float)(B_ * T_);
    float sc = bnw[c] * rsqrtf(var + 1e-5f);
    scalec[c] = sc;
    for (int b = 0; b < B_; ++b)
        obase[b * C_ + c] = (base[b * C_ + c] - mean) * sc + bnb[c];
}

// fill output with column-constant base
__global__ void k_fill(const float* __restrict__ obase, float* __restrict__ out) {
    size_t gid = (size_t)blockIdx.x * 256 + threadIdx.x;
    size_t flat = gid * 4;
    int b = (int)(flat / CT_);
    int c = (int)(flat / T_) & (C_ - 1);
    float v = obase[b * C_ + c];
    float4 o = {v, v, v, v};
    *(float4*)(out + flat) = o;
}

// add spikes: out[b,c,t_i] += scale[c]*down_w[c,e_i]*g_i
__global__ void k_spikes(const float* __restrict__ dw, const float* __restrict__ scalec,
                         const int* __restrict__ sel_e, const int* __restrict__ sel_t,
                         const float* __restrict__ gval, float* __restrict__ out) {
    int gid = blockIdx.x * 256 + threadIdx.x;   // B*K*64 threads
    int s = gid >> 6, cq = (gid & 63) * 4;
    int b = s >> 9, i = s & (K_ - 1);
    int e = sel_e[b * K_ + i], t = sel_t[b * K_ + i];
    float g = gval[b * K_ + i];
#pragma unroll
    for (int q = 0; q < 4; ++q) {
        int c = cq + q;
        atomicAdd(out + (size_t)b * CT_ + (size_t)c * T_ + t,
                  scalec[c] * dw[(size_t)c * E_ + e] * g);
    }
}

extern "C" void kernel_launch(void* const* d_in, const int* in_sizes, int n_in,
                              void* d_out, int out_size, void* d_ws, size_t ws_size,
                              hipStream_t stream) {
    const float* x = (const float*)d_in[0];
    const float* up_w = (const float*)d_in[1];
    const float* up_b = (const float*)d_in[2];
    const float* mask_w = (const float*)d_in[3];
    const float* mask_b = (const float*)d_in[4];
    const float* sum_w = (const float*)d_in[5];
    const float* sum_b = (const float*)d_in[6];
    const float* down_w = (const float*)d_in[7];
    const float* down_b = (const float*)d_in[8];
    const float* bn_w = (const float*)d_in[9];
    const float* bn_b = (const float*)d_in[10];
    float* out = (float*)d_out;

    // workspace layout (float units); small block first, big split buffers last
    float* ws = (float*)d_ws;
    size_t o = 0;
    float* rn = ws + o;   o += (size_t)B_ * T_;
    float* nrm = ws + o;  o += (size_t)B_ * T_;
    float* xs = ws + o;   o += (size_t)B_ * C_ * SCOLS_;
    float* msub = ws + o; o += (size_t)B_ * SUBN_;
    float* tau0 = ws + o; o += B_;
    float* Z = ws + o;    o += B_;
    int* cnt = (int*)(ws + o);   o += B_;
    float* cval = ws + o; o += (size_t)B_ * CAP_;
    int* cidx = (int*)(ws + o);  o += (size_t)B_ * CAP_;
    int* sel_e = (int*)(ws + o); o += (size_t)B_ * K_;
    int* sel_t = (int*)(ws + o); o += (size_t)B_ * K_;
    float* sel_sp = ws + o; o += (size_t)B_ * K_;
    float* gval = ws + o;   o += (size_t)B_ * K_;
    float* base = ws + o;   o += (size_t)B_ * C_;
    float* S1 = ws + o;     o += (size_t)B_ * C_;
    float* Qv = ws + o;     o += (size_t)B_ * C_;
    float* scalec = ws + o; o += C_;
    float* obase = ws + o;  o += (size_t)B_ * C_ + 8;
    ushort* mwh = (ushort*)(ws + o); o += (size_t)E_ * C_ / 2;
    ushort* mwl = (ushort*)(ws + o); o += (size_t)E_ * C_ / 2;
    ushort* xh = (ushort*)(ws + o);  o += (size_t)B_ * T_ * C_ / 2;
    ushort* xl = (ushort*)(ws + o);  o += (size_t)B_ * T_ * C_ / 2;
    bool fast = ws_size >= o * sizeof(float);

    k_rn<<<(B_ * T_) / 256, 256, 0, stream>>>(x, rn, nrm, Z, cnt);
    k_gather<<<(B_ * C_ * SCOLS_) / 256, 256, 0, stream>>>(x, rn, xs);
    k_msub2<<<dim3(SCOLS_ / 64, E_ / 64, B_), 256, 0, stream>>>(xs, mask_w, mask_b, msub);
    k_tau<<<B_, 256, 0, stream>>>(msub, tau0);
    if (fast) {
        k_split_w<<<(E_ * C_ / 8) / 256, 256, 0, stream>>>(mask_w, mwh, mwl);
        k_split_x<<<dim3(T_ / 64, C_ / 64, B_), 256, 0, stream>>>(x, rn, xh, xl);
        k_gemmf<<<(E_ / 64) * (T_ / 64) * B_, 256, 0, stream>>>(
            mwh, mwl, xh, xl, mask_b, tau0, Z, cnt, cval, cidx);
    } else {
        k_gemm<<<dim3(T_ / 64, E_ / 64, B_), 256, 0, stream>>>(
            x, mask_w, mask_b, rn, tau0, Z, cnt, cval, cidx);
    }
    k_select<<<B_, 256, 0, stream>>>(cval, cidx, cnt, Z, sel_e, sel_t, sel_sp);
    if (fast) {
        k_upg2<<<(B_ * K_ * 64) / 256, 256, 0, stream>>>(xh, xl, nrm, up_w, up_b,
                                                         sel_e, sel_t, sel_sp, gval);
    } else {
        k_upg<<<(B_ * K_ * 64) / 256, 256, 0, stream>>>(x, up_w, up_b, sel_e, sel_t,
                                                        sel_sp, gval);
    }
    k_bsq<<<(B_ * C_) / 4, 256, 0, stream>>>(sum_w, sum_b, down_b, down_w,
                                             sel_e, gval, base, S1, Qv);
    k_bnstats<<<1, C_, 0, stream>>>(base, S1, Qv, bn_w, bn_b, scalec, obase);
    k_fill<<<(B_ * CT_ / 4) / 256, 256, 0, stream>>>(obase, out);
    k_spikes<<<(B_ * K_ * 64) / 256, 256, 0, stream>>>(down_w, scalec, sel_e, sel_t,
                                                       gval, out);
}

// Round 8
// 635.831 us; speedup vs baseline: 1.0013x; 1.0013x over previous
//
#include <hip/hip_runtime.h>
#include <hip/hip_bf16.h>

// Problem constants (fixed by the reference)
#define B_ 8
#define C_ 256
#define E_ 512
#define T_ 8192
#define K_ 512
#define CT_ (C_*T_)
#define CAP_ 32768          // candidate capacity per batch (expected ~4100)
#define SUBS_ 64            // t-subsample stride
#define SCOLS_ (T_/SUBS_)   // 128
#define SUBN_ (E_*SCOLS_)   // 65536 subsample points per batch
#define RANK_ 64            // subsample rank -> expected full count ~4096
#define NB1_ 4096           // subsample histogram bins over [-1,1)
#define NB2_ 4096           // selection histogram bins over [0,0.5)

typedef __attribute__((ext_vector_type(8))) short bf16x8;
typedef __attribute__((ext_vector_type(4))) float f32x4;

__device__ __forceinline__ ushort f2bf(float f) {
    __hip_bfloat16 h = __float2bfloat16(f);
    return *reinterpret_cast<ushort*>(&h);
}
__device__ __forceinline__ float bf2f(ushort u) {
    __hip_bfloat16 h = *reinterpret_cast<__hip_bfloat16*>(&u);
    return __bfloat162float(h);
}

// async global->LDS, 16B per lane; LDS dest = wave-uniform base + lane*16
__device__ __forceinline__ void gl16(const void* g, void* l) {
    __builtin_amdgcn_global_load_lds(
        (const __attribute__((address_space(1))) void*)g,
        (__attribute__((address_space(3))) void*)l, 16, 0, 0);
}

// Tiled operand layout (ushort units):
//   W tiles:  [etile(8)][cc(4)][cb(8)][erow(64)][8]   (16384 per etile)
//   X tiles:  [b*128+ttile][cc(4)][cb(8)][trow(64)][8] (16384 per ttile)
// One gl16 instruction = one [cb] block = 64 rows x 16B, contiguous 1KB.

// rn[b,t] = 1/(||x[b,:,t]|| + 1e-8); nrm = ||x|| + 1e-8; block 0 inits Z, cnt
__global__ void k_rn(const float* __restrict__ x, float* __restrict__ rn,
                     float* __restrict__ nrm, float* __restrict__ Z,
                     int* __restrict__ cnt) {
    if (blockIdx.x == 0 && threadIdx.x < B_) {
        Z[threadIdx.x] = 0.f; cnt[threadIdx.x] = 0;
    }
    int gid = blockIdx.x * 256 + threadIdx.x;   // B*T threads
    int b = gid / T_, t = gid % T_;
    const float* xp = x + (size_t)b * CT_ + t;
    float s0 = 0.f, s1 = 0.f, s2 = 0.f, s3 = 0.f;
    for (int c = 0; c < C_; c += 4) {
        float a0 = xp[(size_t)c * T_];
        float a1 = xp[(size_t)(c + 1) * T_];
        float a2 = xp[(size_t)(c + 2) * T_];
        float a3 = xp[(size_t)(c + 3) * T_];
        s0 += a0 * a0; s1 += a1 * a1; s2 += a2 * a2; s3 += a3 * a3;
    }
    float s = (s0 + s1) + (s2 + s3);
    float n = sqrtf(s) + 1e-8f;
    nrm[gid] = n;
    rn[gid] = 1.0f / n;
}

// split mask_w into bf16 hi/lo, TILED layout (coalesced 16B writes)
__global__ void k_split_w(const float* __restrict__ mw, ushort* __restrict__ mwh,
                          ushort* __restrict__ mwl) {
    int idx = blockIdx.x * 256 + threadIdx.x;   // E*C/8 = 16384 threads
    int erow = idx & 63;
    int cb = (idx >> 6) & 7;
    int cc = (idx >> 9) & 3;
    int etile = idx >> 11;
    int e = etile * 64 + erow;
    int c0 = cc * 64 + cb * 8;
    const float* src = mw + (size_t)e * C_ + c0;
    ushort4 h0, l0, h1, l1;
    float v;
    v = src[0]; h0.x = f2bf(v); l0.x = f2bf(v - bf2f(h0.x));
    v = src[1]; h0.y = f2bf(v); l0.y = f2bf(v - bf2f(h0.y));
    v = src[2]; h0.z = f2bf(v); l0.z = f2bf(v - bf2f(h0.z));
    v = src[3]; h0.w = f2bf(v); l0.w = f2bf(v - bf2f(h0.w));
    v = src[4]; h1.x = f2bf(v); l1.x = f2bf(v - bf2f(h1.x));
    v = src[5]; h1.y = f2bf(v); l1.y = f2bf(v - bf2f(h1.y));
    v = src[6]; h1.z = f2bf(v); l1.z = f2bf(v - bf2f(h1.z));
    v = src[7]; h1.w = f2bf(v); l1.w = f2bf(v - bf2f(h1.w));
    *(ushort4*)(mwh + (size_t)idx * 8) = h0;
    *(ushort4*)(mwh + (size_t)idx * 8 + 4) = h1;
    *(ushort4*)(mwl + (size_t)idx * 8) = l0;
    *(ushort4*)(mwl + (size_t)idx * 8 + 4) = l1;
}

// transpose + rn-scale + split into TILED layout:
// xh/xl[(b*128+ttile)*4+cc][cb][trow][8] = bf16split(x[b][c][t]*rn[b][t])
__launch_bounds__(256)
__global__ void k_split_x(const float* __restrict__ x, const float* __restrict__ rn,
                          ushort* __restrict__ xh, ushort* __restrict__ xl) {
    __shared__ float tile[64][76];
    __shared__ float rnv[64];
    int tid = threadIdx.x;
    int ttile = blockIdx.x, cc = blockIdx.y, b = blockIdx.z;
    int t0 = ttile * 64, c0 = cc * 64;
    if (tid < 64) rnv[tid] = rn[b * T_ + t0 + tid];
    const float* xb = x + (size_t)b * CT_;
#pragma unroll
    for (int q = 0; q < 4; ++q) {
        int idx = tid + q * 256;
        int cr = idx >> 4, t4 = (idx & 15) * 4;
        float4 v = *(const float4*)(xb + (size_t)(c0 + cr) * T_ + t0 + t4);
        *(float4*)&tile[cr][t4] = v;
    }
    __syncthreads();
    size_t obase = (((size_t)b * 128 + ttile) * 4 + cc) * 4096;
#pragma unroll
    for (int q = 0; q < 4; ++q) {
        int idx = tid + q * 256;
        int tr = idx >> 4, c4 = (idx & 15) * 4;
        float s = rnv[tr];
        float v0 = tile[c4 + 0][tr] * s;
        float v1 = tile[c4 + 1][tr] * s;
        float v2 = tile[c4 + 2][tr] * s;
        float v3 = tile[c4 + 3][tr] * s;
        ushort4 h, l;
        h.x = f2bf(v0); l.x = f2bf(v0 - bf2f(h.x));
        h.y = f2bf(v1); l.y = f2bf(v1 - bf2f(h.y));
        h.z = f2bf(v2); l.z = f2bf(v2 - bf2f(h.z));
        h.w = f2bf(v3); l.w = f2bf(v3 - bf2f(h.w));
        int cb = c4 >> 3, half = (c4 >> 2) & 1;
        size_t ro = obase + (size_t)cb * 512 + tr * 8 + half * 4;
        *(ushort4*)(xh + ro) = h;
        *(ushort4*)(xl + ro) = l;
    }
}

// gather subsampled, rn-scaled x: xs[b][c][s] = x[b][c][s*64] * rn[b][s*64]
__global__ void k_gather(const float* __restrict__ x, const float* __restrict__ rn,
                         float* __restrict__ xs) {
    int gid = blockIdx.x * 256 + threadIdx.x;   // B*C*SCOLS threads = 262144
    int s = gid & (SCOLS_ - 1);
    int c = (gid >> 7) & (C_ - 1);
    int b = gid >> 15;
    int t = s * SUBS_;
    xs[gid] = x[(size_t)b * CT_ + (size_t)c * T_ + t] * rn[b * T_ + t];
}

// tiled f32 GEMM on compact gathered buffer (small: ~270 MFLOP)
__launch_bounds__(256)
__global__ void k_msub2(const float* __restrict__ xs, const float* __restrict__ mw,
                        const float* __restrict__ mb, float* __restrict__ msub) {
    __shared__ float As[64][68];
    __shared__ float Bs[64][68];
    int tid = threadIdx.x;
    int tx = tid & 15, ty = tid >> 4;
    int s0 = blockIdx.x * 64, e0 = blockIdx.y * 64, b = blockIdx.z;
    const float* xb = xs + (size_t)b * C_ * SCOLS_;
    float acc[4][4] = {};
    for (int c0 = 0; c0 < C_; c0 += 64) {
#pragma unroll
        for (int r = 0; r < 4; ++r) {
            int i = (tid >> 4) + r * 16;
            int kq = (tid & 15) * 4;
            float4 av = *(const float4*)(mw + (size_t)(e0 + i) * C_ + c0 + kq);
            As[kq + 0][i] = av.x; As[kq + 1][i] = av.y;
            As[kq + 2][i] = av.z; As[kq + 3][i] = av.w;
        }
#pragma unroll
        for (int r = 0; r < 4; ++r) {
            int k = (tid >> 4) + r * 16;
            int jq = (tid & 15) * 4;
            *(float4*)(&Bs[k][jq]) =
                *(const float4*)(xb + (size_t)(c0 + k) * SCOLS_ + s0 + jq);
        }
        __syncthreads();
#pragma unroll
        for (int k = 0; k < 64; ++k) {
            float4 a = *(const float4*)(&As[k][ty * 4]);
            float4 bq = *(const float4*)(&Bs[k][tx * 4]);
            float av[4] = {a.x, a.y, a.z, a.w};
            float bv[4] = {bq.x, bq.y, bq.z, bq.w};
#pragma unroll
            for (int ii = 0; ii < 4; ++ii)
#pragma unroll
                for (int jj = 0; jj < 4; ++jj)
                    acc[ii][jj] += av[ii] * bv[jj];
        }
        __syncthreads();
    }
#pragma unroll
    for (int ii = 0; ii < 4; ++ii) {
        float mbv = mb[e0 + ty * 4 + ii];
#pragma unroll
        for (int jj = 0; jj < 4; ++jj) {
            int e = e0 + ty * 4 + ii, s = s0 + tx * 4 + jj;
            msub[(size_t)b * SUBN_ + e * SCOLS_ + s] = acc[ii][jj] + mbv;
        }
    }
}

// per-batch conservative threshold tau0 from subsample rank-64
__global__ void k_tau(const float* __restrict__ msub, float* __restrict__ tau0) {
    __shared__ int h[NB1_];
    __shared__ int part[256];
    int b = blockIdx.x, tid = threadIdx.x;
    for (int i = tid; i < NB1_; i += 256) h[i] = 0;
    __syncthreads();
    const float* mp = msub + b * SUBN_;
    for (int j = tid; j < SUBN_; j += 256) {
        float v = mp[j];
        int bin = (int)((v + 1.0f) * ((float)NB1_ * 0.5f));
        bin = bin < 0 ? 0 : (bin > NB1_ - 1 ? NB1_ - 1 : bin);
        atomicAdd(&h[bin], 1);
    }
    __syncthreads();
    int ps = 0;
    for (int j = 0; j < 16; ++j) ps += h[tid * 16 + j];
    part[tid] = ps;
    __syncthreads();
    if (tid == 0) {
        int cum = 0, bf = 0;
        for (int i = 255; i >= 0; --i) {
            if (cum + part[i] >= RANK_) {
                int cum2 = cum;
                for (int j = 15; j >= 0; --j) {
                    cum2 += h[i * 16 + j];
                    if (cum2 >= RANK_) { bf = i * 16 + j; break; }
                }
                break;
            }
            cum += part[i];
        }
        tau0[b] = (float)bf * (2.0f / (float)NB1_) - 1.0f;  // bin lower edge
    }
}

// ---------------- fast main GEMM: 128x128 tile, 4x deeper per block ----------
// Same proven single-buffer chunk structure (gl16 -> barrier(vmcnt drained)
// -> MFMA -> barrier), 2048 blocks instead of 8192: each block does a 128x128
// output tile = 2x2 of 64-row operand tiles, 4 waves in 2x2, 64KB LDS.
__launch_bounds__(256)
__global__ void k_gemm128(const ushort* __restrict__ mwh, const ushort* __restrict__ mwl,
                          const ushort* __restrict__ xh, const ushort* __restrict__ xl,
                          const float* __restrict__ mb, const float* __restrict__ tau0,
                          float* __restrict__ Z, int* __restrict__ cnt,
                          float* __restrict__ cval, int* __restrict__ cidx) {
    __shared__ ushort S[8][4096];   // Wh0,Wh1,Wl0,Wl1,Xh0,Xh1,Xl0,Xl1 (8KB each)
    __shared__ float red[4];
    int tid = threadIdx.x, lane = tid & 63, w = tid >> 6;
    int f = blockIdx.x;
    int xcd = f & 7, slot = f >> 3;          // XCD grouping: b == xcd
    int eblk = slot & 3, xt = slot >> 2;     // 4 e-blocks adjacent per x-tile
    int xtile = xcd * 64 + xt;               // 0..511 = b*64 + tt
    int b = xtile >> 6, tt = xtile & 63;
    int e0 = eblk * 128, t0 = tt * 128;

    // wave w stages segments 2w and 2w+1 (8 gl16 each per chunk)
    int s0i = w * 2;
    const ushort* segp[2];
#pragma unroll
    for (int j = 0; j < 2; ++j) {
        int s = s0i + j;
        int hl = s & 1;
        const ushort* base;
        if (s < 2)      base = mwh + (size_t)(eblk * 2 + hl) * 16384;
        else if (s < 4) base = mwl + (size_t)(eblk * 2 + hl) * 16384;
        else if (s < 6) base = xh + ((size_t)b * 128 + tt * 2 + hl) * 16384;
        else            base = xl + ((size_t)b * 128 + tt * 2 + hl) * 16384;
        segp[j] = base + lane * 8;
    }

    f32x4 acc[4][4];
#pragma unroll
    for (int m = 0; m < 4; ++m)
#pragma unroll
        for (int n = 0; n < 4; ++n)
            acc[m][n] = (f32x4){0.f, 0.f, 0.f, 0.f};

    int a15 = lane & 15;
    int khalf = lane >> 4;                   // 0..3
    int wr = w >> 1, wc = w & 1;             // wave's 64x64 quadrant

    for (int cc = 0; cc < 4; ++cc) {
#pragma unroll
        for (int j = 0; j < 2; ++j) {
            const ushort* sp = segp[j] + cc * 4096;
            ushort* lp = &S[s0i + j][0];
#pragma unroll
            for (int i = 0; i < 8; ++i)
                gl16(sp + i * 512, lp + i * 512);
        }
        __syncthreads();
#pragma unroll
        for (int ks = 0; ks < 2; ++ks) {
            int cb16 = ks * 4 + khalf;
            bf16x8 ah[4], al[4], bh[4], bl[4];
#pragma unroll
            for (int m = 0; m < 4; ++m) {
                int aoff = (cb16 * 64 + m * 16 + a15) * 16;
                ah[m] = *(const bf16x8*)((const char*)&S[wr][0] + aoff);
                al[m] = *(const bf16x8*)((const char*)&S[2 + wr][0] + aoff);
            }
#pragma unroll
            for (int n = 0; n < 4; ++n) {
                int boff = (cb16 * 64 + n * 16 + a15) * 16;
                bh[n] = *(const bf16x8*)((const char*)&S[4 + wc][0] + boff);
                bl[n] = *(const bf16x8*)((const char*)&S[6 + wc][0] + boff);
            }
#pragma unroll
            for (int m = 0; m < 4; ++m)
#pragma unroll
                for (int n = 0; n < 4; ++n) {
                    acc[m][n] = __builtin_amdgcn_mfma_f32_16x16x32_bf16(ah[m], bh[n], acc[m][n], 0, 0, 0);
                    acc[m][n] = __builtin_amdgcn_mfma_f32_16x16x32_bf16(ah[m], bl[n], acc[m][n], 0, 0, 0);
                    acc[m][n] = __builtin_amdgcn_mfma_f32_16x16x32_bf16(al[m], bh[n], acc[m][n], 0, 0, 0);
                }
        }
        __syncthreads();
    }

    // epilogue: C/D layout col(t)=lane&15, row(e)=(lane>>4)*4+reg
    float tau = tau0[b];
    float zs = 0.f;
    int erow0 = e0 + wr * 64 + (lane >> 4) * 4;
#pragma unroll
    for (int m = 0; m < 4; ++m)
#pragma unroll
        for (int r = 0; r < 4; ++r) {
            int e = erow0 + m * 16 + r;
            float mbe = mb[e];
#pragma unroll
            for (int n = 0; n < 4; ++n) {
                int t = t0 + wc * 64 + n * 16 + a15;
                float v = acc[m][n][r] + mbe;
                zs += __expf(v);
                if (v >= tau) {
                    int pos = atomicAdd(&cnt[b], 1);
                    if (pos < CAP_) {
                        cval[b * CAP_ + pos] = v;
                        cidx[b * CAP_ + pos] = e * T_ + t;
                    }
                }
            }
        }
#pragma unroll
    for (int off = 32; off; off >>= 1) zs += __shfl_xor(zs, off, 64);
    if (lane == 0) red[w] = zs;
    __syncthreads();
    if (tid == 0) atomicAdd(&Z[b], (red[0] + red[1]) + (red[2] + red[3]));
}

// ---------------- fallback main GEMM (R2-proven, used if ws too small) ------
#define PADC 88
__launch_bounds__(256)
__global__ void k_gemm(const float* __restrict__ x, const float* __restrict__ mw,
                       const float* __restrict__ mb, const float* __restrict__ rn,
                       const float* __restrict__ tau0, float* __restrict__ Z,
                       int* __restrict__ cnt, float* __restrict__ cval,
                       int* __restrict__ cidx) {
    __shared__ ushort Ah[64][PADC], Al[64][PADC];
    __shared__ ushort Bh[64][PADC], Bl[64][PADC];
    __shared__ float red[4];
    int tid = threadIdx.x;
    int lane = tid & 63, w = tid >> 6;
    int t0 = blockIdx.x * 64, e0 = blockIdx.y * 64, b = blockIdx.z;
    const float* xb = x + (size_t)b * CT_;
    f32x4 acc[4] = {{0.f,0.f,0.f,0.f},{0.f,0.f,0.f,0.f},
                    {0.f,0.f,0.f,0.f},{0.f,0.f,0.f,0.f}};
    int arow = w * 16 + (lane & 15);
    int koff = (lane >> 4) * 8;

    for (int cc0 = 0; cc0 < C_; cc0 += 64) {
#pragma unroll
        for (int q = 0; q < 4; ++q) {
            int idx = tid + q * 256;
            int er = idx >> 4, c4 = (idx & 15) * 4;
            float4 v = *(const float4*)(mw + (size_t)(e0 + er) * C_ + cc0 + c4);
            ushort4 h, l;
            h.x = f2bf(v.x); l.x = f2bf(v.x - bf2f(h.x));
            h.y = f2bf(v.y); l.y = f2bf(v.y - bf2f(h.y));
            h.z = f2bf(v.z); l.z = f2bf(v.z - bf2f(h.z));
            h.w = f2bf(v.w); l.w = f2bf(v.w - bf2f(h.w));
            *(ushort4*)&Ah[er][c4] = h;
            *(ushort4*)&Al[er][c4] = l;
        }
#pragma unroll
        for (int q = 0; q < 4; ++q) {
            int idx = tid + q * 256;
            int cr = idx >> 4, t4 = (idx & 15) * 4;
            float4 v = *(const float4*)(xb + (size_t)(cc0 + cr) * T_ + t0 + t4);
            float vv[4] = {v.x, v.y, v.z, v.w};
#pragma unroll
            for (int j = 0; j < 4; ++j) {
                ushort h = f2bf(vv[j]);
                Bh[t4 + j][cr] = h;
                Bl[t4 + j][cr] = f2bf(vv[j] - bf2f(h));
            }
        }
        __syncthreads();
#pragma unroll
        for (int ks = 0; ks < 2; ++ks) {
            int cb = ks * 32 + koff;
            bf16x8 ah = *(const bf16x8*)&Ah[arow][cb];
            bf16x8 al = *(const bf16x8*)&Al[arow][cb];
#pragma unroll
            for (int n = 0; n < 4; ++n) {
                int brow = n * 16 + (lane & 15);
                bf16x8 bh = *(const bf16x8*)&Bh[brow][cb];
                bf16x8 bl = *(const bf16x8*)&Bl[brow][cb];
                acc[n] = __builtin_amdgcn_mfma_f32_16x16x32_bf16(ah, bh, acc[n], 0, 0, 0);
                acc[n] = __builtin_amdgcn_mfma_f32_16x16x32_bf16(ah, bl, acc[n], 0, 0, 0);
                acc[n] = __builtin_amdgcn_mfma_f32_16x16x32_bf16(al, bh, acc[n], 0, 0, 0);
            }
        }
        __syncthreads();
    }
    float tau = tau0[b];
    float zs = 0.f;
#pragma unroll
    for (int n = 0; n < 4; ++n) {
        int t = t0 + n * 16 + (lane & 15);
        float rnv = rn[b * T_ + t];
#pragma unroll
        for (int r = 0; r < 4; ++r) {
            int e = e0 + w * 16 + (lane >> 4) * 4 + r;
            float v = acc[n][r] * rnv + mb[e];
            zs += __expf(v);
            if (v >= tau) {
                int pos = atomicAdd(&cnt[b], 1);
                if (pos < CAP_) {
                    cval[b * CAP_ + pos] = v;
                    cidx[b * CAP_ + pos] = e * T_ + t;
                }
            }
        }
    }
#pragma unroll
    for (int off = 32; off; off >>= 1) zs += __shfl_xor(zs, off, 64);
    if (lane == 0) red[w] = zs;
    __syncthreads();
    if (tid == 0) atomicAdd(&Z[b], (red[0] + red[1]) + (red[2] + red[3]));
}

// exact top-K selection among candidates (value desc, index asc on ties)
__launch_bounds__(256)
__global__ void k_select(const float* __restrict__ cval, const int* __restrict__ cidx,
                         const int* __restrict__ cnt, const float* __restrict__ Z,
                         int* __restrict__ sel_e, int* __restrict__ sel_t,
                         float* __restrict__ sel_sp) {
    __shared__ int h[NB2_];
    __shared__ int part[256];
    __shared__ float bl_v[1024];
    __shared__ int bl_i[1024];
    __shared__ int nb, bstar, nabove, outcnt;
    int b = blockIdx.x, tid = threadIdx.x;
    int n = cnt[b]; if (n > CAP_) n = CAP_;
    for (int i = tid; i < NB2_; i += 256) h[i] = 0;
    if (tid == 0) { nb = 0; outcnt = 0; }
    __syncthreads();
    const float* vp = cval + b * CAP_;
    const int* ip = cidx + b * CAP_;
    for (int j = tid; j < n; j += 256) {
        int bin = (int)(vp[j] * ((float)NB2_ * 2.0f));   // [0,0.5) range
        bin = bin < 0 ? 0 : (bin > NB2_ - 1 ? NB2_ - 1 : bin);
        atomicAdd(&h[bin], 1);
    }
    __syncthreads();
    int ps = 0;
    for (int j = 0; j < 16; ++j) ps += h[tid * 16 + j];
    part[tid] = ps;
    __syncthreads();
    if (tid == 0) {
        int cum = 0, bs = 0, na = 0;
        for (int i = 255; i >= 0; --i) {
            if (cum + part[i] >= K_) {
                int cum2 = cum;
                for (int j = 15; j >= 0; --j) {
                    cum2 += h[i * 16 + j];
                    if (cum2 >= K_) { bs = i * 16 + j; na = cum2 - h[i * 16 + j]; break; }
                }
                break;
            }
            cum += part[i];
        }
        bstar = bs; nabove = na;
    }
    __syncthreads();
    int bs = bstar;
    for (int j = tid; j < n; j += 256) {
        float v = vp[j];
        int bin = (int)(v * ((float)NB2_ * 2.0f));
        bin = bin < 0 ? 0 : (bin > NB2_ - 1 ? NB2_ - 1 : bin);
        if (bin == bs) {
            int q = atomicAdd(&nb, 1);
            if (q < 1024) { bl_v[q] = v; bl_i[q] = ip[j]; }
        }
    }
    __syncthreads();
    float rZ = 1.0f / Z[b];
    for (int j = tid; j < n; j += 256) {
        float v = vp[j];
        int bin = (int)(v * ((float)NB2_ * 2.0f));
        bin = bin < 0 ? 0 : (bin > NB2_ - 1 ? NB2_ - 1 : bin);
        if (bin > bs) {
            int q = atomicAdd(&outcnt, 1);
            int idx = ip[j];
            sel_e[b * K_ + q] = idx / T_;
            sel_t[b * K_ + q] = idx % T_;
            sel_sp[b * K_ + q] = __expf(v) * rZ;
        }
    }
    __syncthreads();
    if (tid == 0) {
        int m = nb; if (m > 1024) m = 1024;
        for (int i = 1; i < m; ++i) {          // insertion sort: val desc, idx asc
            float v = bl_v[i]; int id = bl_i[i]; int j = i - 1;
            while (j >= 0 && (bl_v[j] < v || (bl_v[j] == v && bl_i[j] > id))) {
                bl_v[j + 1] = bl_v[j]; bl_i[j + 1] = bl_i[j]; --j;
            }
            bl_v[j + 1] = v; bl_i[j + 1] = id;
        }
        int need = K_ - nabove;
        for (int q = 0; q < need; ++q) {
            int slot = nabove + q;
            if (q < m) {
                int idx = bl_i[q];
                sel_e[b * K_ + slot] = idx / T_;
                sel_t[b * K_ + slot] = idx % T_;
                sel_sp[b * K_ + slot] = __expf(bl_v[q]) * rZ;
            } else {  // pathological fallback: harmless zero entries
                sel_e[b * K_ + slot] = 0; sel_t[b * K_ + slot] = 0;
                sel_sp[b * K_ + slot] = 0.f;
            }
        }
    }
}

// up at selected positions via tiled split-x:
// up = (sum_c uw[c]*(xh+xl)[t][c]) * nrm[t];  g = sp * (up + up_b)
__global__ void k_upg2(const ushort* __restrict__ xh, const ushort* __restrict__ xl,
                       const float* __restrict__ nrm, const float* __restrict__ uw,
                       const float* __restrict__ ub, const int* __restrict__ sel_e,
                       const int* __restrict__ sel_t, const float* __restrict__ sel_sp,
                       float* __restrict__ gval) {
    int gid = blockIdx.x * 256 + threadIdx.x;   // B*K waves
    int w = gid >> 6, lane = gid & 63;
    int b = w >> 9, i = w & (K_ - 1);
    int e = sel_e[b * K_ + i], t = sel_t[b * K_ + i];
    int ttile = t >> 6, trow = t & 63;
    int cc = lane >> 4, cb = (lane >> 1) & 7, half = lane & 1;
    size_t ro = ((((size_t)b * 128 + ttile) * 4 + cc) * 8 + cb) * 512
              + (size_t)trow * 8 + half * 4;          // c = lane*4 .. +4
    ushort4 h = *(const ushort4*)(xh + ro);
    ushort4 l = *(const ushort4*)(xl + ro);
    float4 wv = *(const float4*)(uw + (size_t)e * C_ + lane * 4);
    float acc = (bf2f(h.x) + bf2f(l.x)) * wv.x + (bf2f(h.y) + bf2f(l.y)) * wv.y
              + (bf2f(h.z) + bf2f(l.z)) * wv.z + (bf2f(h.w) + bf2f(l.w)) * wv.w;
#pragma unroll
    for (int off = 32; off; off >>= 1) acc += __shfl_down(acc, off, 64);
    if (lane == 0)
        gval[b * K_ + i] = sel_sp[b * K_ + i] * (acc * nrm[b * T_ + t] + ub[e]);
}

// fallback k_upg (raw x, strided)
__global__ void k_upg(const float* __restrict__ x, const float* __restrict__ uw,
                      const float* __restrict__ ub, const int* __restrict__ sel_e,
                      const int* __restrict__ sel_t, const float* __restrict__ sel_sp,
                      float* __restrict__ gval) {
    int gid = blockIdx.x * 256 + threadIdx.x;   // B*K waves
    int w = gid >> 6, lane = gid & 63;
    int b = w >> 9, i = w & (K_ - 1);
    int e = sel_e[b * K_ + i], t = sel_t[b * K_ + i];
    const float* xp = x + (size_t)b * CT_ + t;
    const float* wp = uw + (size_t)e * C_;
    float acc = 0.f;
    for (int c = lane; c < C_; c += 64) acc += wp[c] * xp[(size_t)c * T_];
    for (int off = 32; off; off >>= 1) acc += __shfl_down(acc, off, 64);
    if (lane == 0) gval[b * K_ + i] = sel_sp[b * K_ + i] * (acc + ub[e]);
}

// merged base + S1/Q: one wave per (b,c)
__global__ void k_bsq(const float* __restrict__ sw, const float* __restrict__ sb,
                      const float* __restrict__ db, const float* __restrict__ dw,
                      const int* __restrict__ sel_e, const float* __restrict__ gval,
                      float* __restrict__ base, float* __restrict__ S1,
                      float* __restrict__ Qv) {
    int wg = blockIdx.x * 4 + (threadIdx.x >> 6);   // 2048 waves
    int lane = threadIdx.x & 63;
    int b = wg >> 8, c = wg & (C_ - 1);
    float p = 0.f, s = 0.f, q = 0.f;
    for (int i = lane; i < K_; i += 64) {
        int e = sel_e[b * K_ + i];
        float g = gval[b * K_ + i];
        p += g * sw[(size_t)c * E_ + e];
        float wv = dw[(size_t)c * E_ + e] * g;
        s += wv; q += wv * wv;
    }
#pragma unroll
    for (int off = 32; off; off >>= 1) {
        p += __shfl_xor(p, off, 64);
        s += __shfl_xor(s, off, 64);
        q += __shfl_xor(q, off, 64);
    }
    if (lane == 0) {
        base[b * C_ + c] = p + sb[c] + db[c];
        S1[b * C_ + c] = s; Qv[b * C_ + c] = q;
    }
}

// BN stats analytic: mean/var per channel, then scale + per-(b,c) output base
__global__ void k_bnstats(const float* __restrict__ base, const float* __restrict__ S1,
                          const float* __restrict__ Qv, const float* __restrict__ bnw,
                          const float* __restrict__ bnb, float* __restrict__ scalec,
                          float* __restrict__ obase) {
    int c = threadIdx.x;
    float msum = 0.f;
    for (int b = 0; b < B_; ++b) msum += (float)T_ * base[b * C_ + c] + S1[b * C_ + c];
    float mean = msum / (float)(B_ * T_);
    float vs = 0.f;
    for (int b = 0; b < B_; ++b) {
        float d = base[b * C_ + c] - mean;
        vs += (float)T_ * d * d + 2.0f * d * S1[b * C_ + c] + Qv[b * C_ + c];
    }
    float var = vs / (float)(B_ * T_);
    float sc = bnw[c] * rsqrtf(var + 1e-5f);
    scalec[c] = sc;
    for (int b = 0; b < B_; ++b)
        obase[b * C_ + c] = (base[b * C_ + c] - mean) * sc + bnb[c];
}

// fill output with column-constant base
__global__ void k_fill(const float* __restrict__ obase, float* __restrict__ out) {
    size_t gid = (size_t)blockIdx.x * 256 + threadIdx.x;
    size_t flat = gid * 4;
    int b = (int)(flat / CT_);
    int c = (int)(flat / T_) & (C_ - 1);
    float v = obase[b * C_ + c];
    float4 o = {v, v, v, v};
    *(float4*)(out + flat) = o;
}

// add spikes: out[b,c,t_i] += scale[c]*down_w[c,e_i]*g_i
__global__ void k_spikes(const float* __restrict__ dw, const float* __restrict__ scalec,
                         const int* __restrict__ sel_e, const int* __restrict__ sel_t,
                         const float* __restrict__ gval, float* __restrict__ out) {
    int gid = blockIdx.x * 256 + threadIdx.x;   // B*K*64 threads
    int s = gid >> 6, cq = (gid & 63) * 4;
    int b = s >> 9, i = s & (K_ - 1);
    int e = sel_e[b * K_ + i], t = sel_t[b * K_ + i];
    float g = gval[b * K_ + i];
#pragma unroll
    for (int q = 0; q < 4; ++q) {
        int c = cq + q;
        atomicAdd(out + (size_t)b * CT_ + (size_t)c * T_ + t,
                  scalec[c] * dw[(size_t)c * E_ + e] * g);
    }
}

extern "C" void kernel_launch(void* const* d_in, const int* in_sizes, int n_in,
                              void* d_out, int out_size, void* d_ws, size_t ws_size,
                              hipStream_t stream) {
    const float* x = (const float*)d_in[0];
    const float* up_w = (const float*)d_in[1];
    const float* up_b = (const float*)d_in[2];
    const float* mask_w = (const float*)d_in[3];
    const float* mask_b = (const float*)d_in[4];
    const float* sum_w = (const float*)d_in[5];
    const float* sum_b = (const float*)d_in[6];
    const float* down_w = (const float*)d_in[7];
    const float* down_b = (const float*)d_in[8];
    const float* bn_w = (const float*)d_in[9];
    const float* bn_b = (const float*)d_in[10];
    float* out = (float*)d_out;

    // workspace layout (float units); small block first, big split buffers last
    float* ws = (float*)d_ws;
    size_t o = 0;
    float* rn = ws + o;   o += (size_t)B_ * T_;
    float* nrm = ws + o;  o += (size_t)B_ * T_;
    float* xs = ws + o;   o += (size_t)B_ * C_ * SCOLS_;
    float* msub = ws + o; o += (size_t)B_ * SUBN_;
    float* tau0 = ws + o; o += B_;
    float* Z = ws + o;    o += B_;
    int* cnt = (int*)(ws + o);   o += B_;
    float* cval = ws + o; o += (size_t)B_ * CAP_;
    int* cidx = (int*)(ws + o);  o += (size_t)B_ * CAP_;
    int* sel_e = (int*)(ws + o); o += (size_t)B_ * K_;
    int* sel_t = (int*)(ws + o); o += (size_t)B_ * K_;
    float* sel_sp = ws + o; o += (size_t)B_ * K_;
    float* gval = ws + o;   o += (size_t)B_ * K_;
    float* base = ws + o;   o += (size_t)B_ * C_;
    float* S1 = ws + o;     o += (size_t)B_ * C_;
    float* Qv = ws + o;     o += (size_t)B_ * C_;
    float* scalec = ws + o; o += C_;
    float* obase = ws + o;  o += (size_t)B_ * C_ + 8;
    ushort* mwh = (ushort*)(ws + o); o += (size_t)E_ * C_ / 2;
    ushort* mwl = (ushort*)(ws + o); o += (size_t)E_ * C_ / 2;
    ushort* xh = (ushort*)(ws + o);  o += (size_t)B_ * T_ * C_ / 2;
    ushort* xl = (ushort*)(ws + o);  o += (size_t)B_ * T_ * C_ / 2;
    bool fast = ws_size >= o * sizeof(float);

    k_rn<<<(B_ * T_) / 256, 256, 0, stream>>>(x, rn, nrm, Z, cnt);
    k_gather<<<(B_ * C_ * SCOLS_) / 256, 256, 0, stream>>>(x, rn, xs);
    k_msub2<<<dim3(SCOLS_ / 64, E_ / 64, B_), 256, 0, stream>>>(xs, mask_w, mask_b, msub);
    k_tau<<<B_, 256, 0, stream>>>(msub, tau0);
    if (fast) {
        k_split_w<<<(E_ * C_ / 8) / 256, 256, 0, stream>>>(mask_w, mwh, mwl);
        k_split_x<<<dim3(T_ / 64, C_ / 64, B_), 256, 0, stream>>>(x, rn, xh, xl);
        k_gemm128<<<(E_ / 128) * (T_ / 128) * B_, 256, 0, stream>>>(
            mwh, mwl, xh, xl, mask_b, tau0, Z, cnt, cval, cidx);
    } else {
        k_gemm<<<dim3(T_ / 64, E_ / 64, B_), 256, 0, stream>>>(
            x, mask_w, mask_b, rn, tau0, Z, cnt, cval, cidx);
    }
    k_select<<<B_, 256, 0, stream>>>(cval, cidx, cnt, Z, sel_e, sel_t, sel_sp);
    if (fast) {
        k_upg2<<<(B_ * K_ * 64) / 256, 256, 0, stream>>>(xh, xl, nrm, up_w, up_b,
                                                         sel_e, sel_t, sel_sp, gval);
    } else {
        k_upg<<<(B_ * K_ * 64) / 256, 256, 0, stream>>>(x, up_w, up_b, sel_e, sel_t,
                                                        sel_sp, gval);
    }
    k_bsq<<<(B_ * C_) / 4, 256, 0, stream>>>(sum_w, sum_b, down_b, down_w,
                                             sel_e, gval, base, S1, Qv);
    k_bnstats<<<1, C_, 0, stream>>>(base, S1, Qv, bn_w, bn_b, scalec, obase);
    k_fill<<<(B_ * CT_ / 4) / 256, 256, 0, stream>>>(obase, out);
    k_spikes<<<(B_ * K_ * 64) / 256, 256, 0, stream>>>(down_w, scalec, sel_e, sel_t,
                                                       gval, out);
}

// Round 9
// 323.033 us; speedup vs baseline: 1.9709x; 1.9683x over previous
//
#include <hip/hip_runtime.h>
#include <hip/hip_bf16.h>

// Problem constants (fixed by the reference)
#define B_ 8
#define C_ 256
#define E_ 512
#define T_ 8192
#define K_ 512
#define CT_ (C_*T_)
#define CAP_ 32768          // compacted candidate capacity per batch
#define BCAP_ 512           // per-block LDS candidate capacity (expected ~20)
#define OCAP_ 1024          // per-batch overflow capacity
#define NBLK_ 2048          // k_gemm128 grid
#define SUBS_ 64            // t-subsample stride
#define SCOLS_ (T_/SUBS_)   // 128
#define SUBN_ (E_*SCOLS_)   // 65536 subsample points per batch
#define RANK_ 64            // subsample rank -> expected full count ~4096
#define NB1_ 4096           // subsample histogram bins over [-1,1)
#define NB2_ 4096           // selection histogram bins over [0,0.5)

typedef __attribute__((ext_vector_type(8))) short bf16x8;
typedef __attribute__((ext_vector_type(4))) float f32x4;

__device__ __forceinline__ ushort f2bf(float f) {
    __hip_bfloat16 h = __float2bfloat16(f);
    return *reinterpret_cast<ushort*>(&h);
}
__device__ __forceinline__ float bf2f(ushort u) {
    __hip_bfloat16 h = *reinterpret_cast<__hip_bfloat16*>(&u);
    return __bfloat162float(h);
}

// async global->LDS, 16B per lane; LDS dest = wave-uniform base + lane*16
__device__ __forceinline__ void gl16(const void* g, void* l) {
    __builtin_amdgcn_global_load_lds(
        (const __attribute__((address_space(1))) void*)g,
        (__attribute__((address_space(3))) void*)l, 16, 0, 0);
}

// Tiled operand layout (ushort units):
//   W tiles:  [etile(8)][cc(4)][cb(8)][erow(64)][8]   (16384 per etile)
//   X tiles:  [b*128+ttile][cc(4)][cb(8)][trow(64)][8] (16384 per ttile)

// rn/nrm; block 0 inits Z, cnt, ovc
__global__ void k_rn(const float* __restrict__ x, float* __restrict__ rn,
                     float* __restrict__ nrm, float* __restrict__ Z,
                     int* __restrict__ cnt, int* __restrict__ ovc) {
    if (blockIdx.x == 0 && threadIdx.x < B_) {
        Z[threadIdx.x] = 0.f; cnt[threadIdx.x] = 0; ovc[threadIdx.x] = 0;
    }
    int gid = blockIdx.x * 256 + threadIdx.x;   // B*T threads
    int b = gid / T_, t = gid % T_;
    const float* xp = x + (size_t)b * CT_ + t;
    float s0 = 0.f, s1 = 0.f, s2 = 0.f, s3 = 0.f;
    for (int c = 0; c < C_; c += 4) {
        float a0 = xp[(size_t)c * T_];
        float a1 = xp[(size_t)(c + 1) * T_];
        float a2 = xp[(size_t)(c + 2) * T_];
        float a3 = xp[(size_t)(c + 3) * T_];
        s0 += a0 * a0; s1 += a1 * a1; s2 += a2 * a2; s3 += a3 * a3;
    }
    float s = (s0 + s1) + (s2 + s3);
    float n = sqrtf(s) + 1e-8f;
    nrm[gid] = n;
    rn[gid] = 1.0f / n;
}

// split mask_w into bf16 hi/lo, TILED layout (coalesced 16B writes)
__global__ void k_split_w(const float* __restrict__ mw, ushort* __restrict__ mwh,
                          ushort* __restrict__ mwl) {
    int idx = blockIdx.x * 256 + threadIdx.x;   // E*C/8 = 16384 threads
    int erow = idx & 63;
    int cb = (idx >> 6) & 7;
    int cc = (idx >> 9) & 3;
    int etile = idx >> 11;
    int e = etile * 64 + erow;
    int c0 = cc * 64 + cb * 8;
    const float* src = mw + (size_t)e * C_ + c0;
    ushort4 h0, l0, h1, l1;
    float v;
    v = src[0]; h0.x = f2bf(v); l0.x = f2bf(v - bf2f(h0.x));
    v = src[1]; h0.y = f2bf(v); l0.y = f2bf(v - bf2f(h0.y));
    v = src[2]; h0.z = f2bf(v); l0.z = f2bf(v - bf2f(h0.z));
    v = src[3]; h0.w = f2bf(v); l0.w = f2bf(v - bf2f(h0.w));
    v = src[4]; h1.x = f2bf(v); l1.x = f2bf(v - bf2f(h1.x));
    v = src[5]; h1.y = f2bf(v); l1.y = f2bf(v - bf2f(h1.y));
    v = src[6]; h1.z = f2bf(v); l1.z = f2bf(v - bf2f(h1.z));
    v = src[7]; h1.w = f2bf(v); l1.w = f2bf(v - bf2f(h1.w));
    *(ushort4*)(mwh + (size_t)idx * 8) = h0;
    *(ushort4*)(mwh + (size_t)idx * 8 + 4) = h1;
    *(ushort4*)(mwl + (size_t)idx * 8) = l0;
    *(ushort4*)(mwl + (size_t)idx * 8 + 4) = l1;
}

// transpose + rn-scale + split into TILED layout
__launch_bounds__(256)
__global__ void k_split_x(const float* __restrict__ x, const float* __restrict__ rn,
                          ushort* __restrict__ xh, ushort* __restrict__ xl) {
    __shared__ float tile[64][76];
    __shared__ float rnv[64];
    int tid = threadIdx.x;
    int ttile = blockIdx.x, cc = blockIdx.y, b = blockIdx.z;
    int t0 = ttile * 64, c0 = cc * 64;
    if (tid < 64) rnv[tid] = rn[b * T_ + t0 + tid];
    const float* xb = x + (size_t)b * CT_;
#pragma unroll
    for (int q = 0; q < 4; ++q) {
        int idx = tid + q * 256;
        int cr = idx >> 4, t4 = (idx & 15) * 4;
        float4 v = *(const float4*)(xb + (size_t)(c0 + cr) * T_ + t0 + t4);
        *(float4*)&tile[cr][t4] = v;
    }
    __syncthreads();
    size_t obase = (((size_t)b * 128 + ttile) * 4 + cc) * 4096;
#pragma unroll
    for (int q = 0; q < 4; ++q) {
        int idx = tid + q * 256;
        int tr = idx >> 4, c4 = (idx & 15) * 4;
        float s = rnv[tr];
        float v0 = tile[c4 + 0][tr] * s;
        float v1 = tile[c4 + 1][tr] * s;
        float v2 = tile[c4 + 2][tr] * s;
        float v3 = tile[c4 + 3][tr] * s;
        ushort4 h, l;
        h.x = f2bf(v0); l.x = f2bf(v0 - bf2f(h.x));
        h.y = f2bf(v1); l.y = f2bf(v1 - bf2f(h.y));
        h.z = f2bf(v2); l.z = f2bf(v2 - bf2f(h.z));
        h.w = f2bf(v3); l.w = f2bf(v3 - bf2f(h.w));
        int cb = c4 >> 3, half = (c4 >> 2) & 1;
        size_t ro = obase + (size_t)cb * 512 + tr * 8 + half * 4;
        *(ushort4*)(xh + ro) = h;
        *(ushort4*)(xl + ro) = l;
    }
}

// gather subsampled, rn-scaled x
__global__ void k_gather(const float* __restrict__ x, const float* __restrict__ rn,
                         float* __restrict__ xs) {
    int gid = blockIdx.x * 256 + threadIdx.x;   // B*C*SCOLS threads = 262144
    int s = gid & (SCOLS_ - 1);
    int c = (gid >> 7) & (C_ - 1);
    int b = gid >> 15;
    int t = s * SUBS_;
    xs[gid] = x[(size_t)b * CT_ + (size_t)c * T_ + t] * rn[b * T_ + t];
}

// tiled f32 GEMM on compact gathered buffer (small: ~270 MFLOP)
__launch_bounds__(256)
__global__ void k_msub2(const float* __restrict__ xs, const float* __restrict__ mw,
                        const float* __restrict__ mb, float* __restrict__ msub) {
    __shared__ float As[64][68];
    __shared__ float Bs[64][68];
    int tid = threadIdx.x;
    int tx = tid & 15, ty = tid >> 4;
    int s0 = blockIdx.x * 64, e0 = blockIdx.y * 64, b = blockIdx.z;
    const float* xb = xs + (size_t)b * C_ * SCOLS_;
    float acc[4][4] = {};
    for (int c0 = 0; c0 < C_; c0 += 64) {
#pragma unroll
        for (int r = 0; r < 4; ++r) {
            int i = (tid >> 4) + r * 16;
            int kq = (tid & 15) * 4;
            float4 av = *(const float4*)(mw + (size_t)(e0 + i) * C_ + c0 + kq);
            As[kq + 0][i] = av.x; As[kq + 1][i] = av.y;
            As[kq + 2][i] = av.z; As[kq + 3][i] = av.w;
        }
#pragma unroll
        for (int r = 0; r < 4; ++r) {
            int k = (tid >> 4) + r * 16;
            int jq = (tid & 15) * 4;
            *(float4*)(&Bs[k][jq]) =
                *(const float4*)(xb + (size_t)(c0 + k) * SCOLS_ + s0 + jq);
        }
        __syncthreads();
#pragma unroll
        for (int k = 0; k < 64; ++k) {
            float4 a = *(const float4*)(&As[k][ty * 4]);
            float4 bq = *(const float4*)(&Bs[k][tx * 4]);
            float av[4] = {a.x, a.y, a.z, a.w};
            float bv[4] = {bq.x, bq.y, bq.z, bq.w};
#pragma unroll
            for (int ii = 0; ii < 4; ++ii)
#pragma unroll
                for (int jj = 0; jj < 4; ++jj)
                    acc[ii][jj] += av[ii] * bv[jj];
        }
        __syncthreads();
    }
#pragma unroll
    for (int ii = 0; ii < 4; ++ii) {
        float mbv = mb[e0 + ty * 4 + ii];
#pragma unroll
        for (int jj = 0; jj < 4; ++jj) {
            int e = e0 + ty * 4 + ii, s = s0 + tx * 4 + jj;
            msub[(size_t)b * SUBN_ + e * SCOLS_ + s] = acc[ii][jj] + mbv;
        }
    }
}

// per-batch conservative threshold tau0 from subsample rank-64
__global__ void k_tau(const float* __restrict__ msub, float* __restrict__ tau0) {
    __shared__ int h[NB1_];
    __shared__ int part[256];
    int b = blockIdx.x, tid = threadIdx.x;
    for (int i = tid; i < NB1_; i += 256) h[i] = 0;
    __syncthreads();
    const float* mp = msub + b * SUBN_;
    for (int j = tid; j < SUBN_; j += 256) {
        float v = mp[j];
        int bin = (int)((v + 1.0f) * ((float)NB1_ * 0.5f));
        bin = bin < 0 ? 0 : (bin > NB1_ - 1 ? NB1_ - 1 : bin);
        atomicAdd(&h[bin], 1);
    }
    __syncthreads();
    int ps = 0;
    for (int j = 0; j < 16; ++j) ps += h[tid * 16 + j];
    part[tid] = ps;
    __syncthreads();
    if (tid == 0) {
        int cum = 0, bf = 0;
        for (int i = 255; i >= 0; --i) {
            if (cum + part[i] >= RANK_) {
                int cum2 = cum;
                for (int j = 15; j >= 0; --j) {
                    cum2 += h[i * 16 + j];
                    if (cum2 >= RANK_) { bf = i * 16 + j; break; }
                }
                break;
            }
            cum += part[i];
        }
        tau0[b] = (float)bf * (2.0f / (float)NB1_) - 1.0f;  // bin lower edge
    }
}

// ---------------- fast main GEMM: 128x128 tile, NO global atomics -----------
// R7-proven K-loop verbatim. Epilogue: candidates -> LDS (shared count +
// 512-slot buffer, plain-store flush to per-block region); Z partial ->
// plain store. Global atomics only on (rare) per-block overflow.
__launch_bounds__(256)
__global__ void k_gemm128(const ushort* __restrict__ mwh, const ushort* __restrict__ mwl,
                          const ushort* __restrict__ xh, const ushort* __restrict__ xl,
                          const float* __restrict__ mb, const float* __restrict__ tau0,
                          float* __restrict__ zpart, int* __restrict__ cntB,
                          float* __restrict__ cvalB, int* __restrict__ cidxB,
                          int* __restrict__ ovc, float* __restrict__ ovv,
                          int* __restrict__ ovi) {
    __shared__ ushort S[8][4096];   // Wh0,Wh1,Wl0,Wl1,Xh0,Xh1,Xl0,Xl1 (8KB each)
    __shared__ float red[4];
    __shared__ float sval[BCAP_];
    __shared__ int sidx[BCAP_];
    __shared__ int scnt;
    int tid = threadIdx.x, lane = tid & 63, w = tid >> 6;
    int f = blockIdx.x;
    int xcd = f & 7, slot = f >> 3;          // XCD grouping: b == xcd
    int eblk = slot & 3, xt = slot >> 2;     // 4 e-blocks adjacent per x-tile
    int xtile = xcd * 64 + xt;               // 0..511 = b*64 + tt
    int b = xtile >> 6, tt = xtile & 63;
    int e0 = eblk * 128, t0 = tt * 128;
    if (tid == 0) scnt = 0;

    // wave w stages segments 2w and 2w+1 (8 gl16 each per chunk)
    int s0i = w * 2;
    const ushort* segp[2];
#pragma unroll
    for (int j = 0; j < 2; ++j) {
        int s = s0i + j;
        int hl = s & 1;
        const ushort* base;
        if (s < 2)      base = mwh + (size_t)(eblk * 2 + hl) * 16384;
        else if (s < 4) base = mwl + (size_t)(eblk * 2 + hl) * 16384;
        else if (s < 6) base = xh + ((size_t)b * 128 + tt * 2 + hl) * 16384;
        else            base = xl + ((size_t)b * 128 + tt * 2 + hl) * 16384;
        segp[j] = base + lane * 8;
    }

    f32x4 acc[4][4];
#pragma unroll
    for (int m = 0; m < 4; ++m)
#pragma unroll
        for (int n = 0; n < 4; ++n)
            acc[m][n] = (f32x4){0.f, 0.f, 0.f, 0.f};

    int a15 = lane & 15;
    int khalf = lane >> 4;                   // 0..3
    int wr = w >> 1, wc = w & 1;             // wave's 64x64 quadrant

    for (int cc = 0; cc < 4; ++cc) {
#pragma unroll
        for (int j = 0; j < 2; ++j) {
            const ushort* sp = segp[j] + cc * 4096;
            ushort* lp = &S[s0i + j][0];
#pragma unroll
            for (int i = 0; i < 8; ++i)
                gl16(sp + i * 512, lp + i * 512);
        }
        __syncthreads();
#pragma unroll
        for (int ks = 0; ks < 2; ++ks) {
            int cb16 = ks * 4 + khalf;
            bf16x8 ah[4], al[4], bh[4], bl[4];
#pragma unroll
            for (int m = 0; m < 4; ++m) {
                int aoff = (cb16 * 64 + m * 16 + a15) * 16;
                ah[m] = *(const bf16x8*)((const char*)&S[wr][0] + aoff);
                al[m] = *(const bf16x8*)((const char*)&S[2 + wr][0] + aoff);
            }
#pragma unroll
            for (int n = 0; n < 4; ++n) {
                int boff = (cb16 * 64 + n * 16 + a15) * 16;
                bh[n] = *(const bf16x8*)((const char*)&S[4 + wc][0] + boff);
                bl[n] = *(const bf16x8*)((const char*)&S[6 + wc][0] + boff);
            }
#pragma unroll
            for (int m = 0; m < 4; ++m)
#pragma unroll
                for (int n = 0; n < 4; ++n) {
                    acc[m][n] = __builtin_amdgcn_mfma_f32_16x16x32_bf16(ah[m], bh[n], acc[m][n], 0, 0, 0);
                    acc[m][n] = __builtin_amdgcn_mfma_f32_16x16x32_bf16(ah[m], bl[n], acc[m][n], 0, 0, 0);
                    acc[m][n] = __builtin_amdgcn_mfma_f32_16x16x32_bf16(al[m], bh[n], acc[m][n], 0, 0, 0);
                }
        }
        __syncthreads();
    }

    // epilogue: C/D layout col(t)=lane&15, row(e)=(lane>>4)*4+reg
    float tau = tau0[b];
    float zs = 0.f;
    int erow0 = e0 + wr * 64 + (lane >> 4) * 4;
#pragma unroll
    for (int m = 0; m < 4; ++m)
#pragma unroll
        for (int r = 0; r < 4; ++r) {
            int e = erow0 + m * 16 + r;
            float mbe = mb[e];
#pragma unroll
            for (int n = 0; n < 4; ++n) {
                int t = t0 + wc * 64 + n * 16 + a15;
                float v = acc[m][n][r] + mbe;
                zs += __expf(v);
                if (v >= tau) {
                    int pos = atomicAdd(&scnt, 1);       // LDS atomic (fast)
                    if (pos < BCAP_) {
                        sval[pos] = v;
                        sidx[pos] = e * T_ + t;
                    } else {                             // rare overflow spill
                        int q = atomicAdd(&ovc[b], 1);
                        if (q < OCAP_) {
                            ovv[b * OCAP_ + q] = v;
                            ovi[b * OCAP_ + q] = e * T_ + t;
                        }
                    }
                }
            }
        }
#pragma unroll
    for (int off = 32; off; off >>= 1) zs += __shfl_xor(zs, off, 64);
    if (lane == 0) red[w] = zs;
    __syncthreads();
    // flush: plain stores only
    int nc = scnt < BCAP_ ? scnt : BCAP_;
    for (int j = tid; j < nc; j += 256) {
        cvalB[(size_t)f * BCAP_ + j] = sval[j];
        cidxB[(size_t)f * BCAP_ + j] = sidx[j];
    }
    if (tid == 0) {
        cntB[f] = nc;
        zpart[f] = (red[0] + red[1]) + (red[2] + red[3]);
    }
}

// compact per-block candidate regions into per-batch arrays; sum Z
__launch_bounds__(256)
__global__ void k_compact(const float* __restrict__ zpart, const int* __restrict__ cntB,
                          const float* __restrict__ cvalB, const int* __restrict__ cidxB,
                          const int* __restrict__ ovc, const float* __restrict__ ovv,
                          const int* __restrict__ ovi, float* __restrict__ Z,
                          int* __restrict__ cnt, float* __restrict__ cval,
                          int* __restrict__ cidx) {
    __shared__ int pre[256];
    __shared__ float zs[256];
    int b = blockIdx.x, tid = threadIdx.x;   // 256 threads, 256 regions/batch
    int f = b + 8 * tid;                     // region id (b == f&7 decode)
    int c = cntB[f];
    pre[tid] = c;
    zs[tid] = zpart[f];
    __syncthreads();
    // inclusive scan (Hillis-Steele) on pre
    for (int d = 1; d < 256; d <<= 1) {
        int v = (tid >= d) ? pre[tid - d] : 0;
        __syncthreads();
        pre[tid] += v;
        __syncthreads();
    }
    int start = pre[tid] - c;                // exclusive prefix
    int total = pre[255];
    for (int j = 0; j < c; ++j) {
        int d = start + j;
        if (d < CAP_) {
            cval[b * CAP_ + d] = cvalB[(size_t)f * BCAP_ + j];
            cidx[b * CAP_ + d] = cidxB[(size_t)f * BCAP_ + j];
        }
    }
    // Z reduction
    __syncthreads();
    for (int d = 128; d; d >>= 1) {
        if (tid < d) zs[tid] += zs[tid + d];
        __syncthreads();
    }
    // append overflow (usually 0)
    int no = ovc[b]; if (no > OCAP_) no = OCAP_;
    for (int j = tid; j < no; j += 256) {
        int d = total + j;
        if (d < CAP_) {
            cval[b * CAP_ + d] = ovv[b * OCAP_ + j];
            cidx[b * CAP_ + d] = ovi[b * OCAP_ + j];
        }
    }
    if (tid == 0) {
        int tot = total + no;
        cnt[b] = tot < CAP_ ? tot : CAP_;
        Z[b] = zs[0];
    }
}

// ---------------- fallback main GEMM (R2-proven, used if ws too small) ------
#define PADC 88
__launch_bounds__(256)
__global__ void k_gemm(const float* __restrict__ x, const float* __restrict__ mw,
                       const float* __restrict__ mb, const float* __restrict__ rn,
                       const float* __restrict__ tau0, float* __restrict__ Z,
                       int* __restrict__ cnt, float* __restrict__ cval,
                       int* __restrict__ cidx) {
    __shared__ ushort Ah[64][PADC], Al[64][PADC];
    __shared__ ushort Bh[64][PADC], Bl[64][PADC];
    __shared__ float red[4];
    int tid = threadIdx.x;
    int lane = tid & 63, w = tid >> 6;
    int t0 = blockIdx.x * 64, e0 = blockIdx.y * 64, b = blockIdx.z;
    const float* xb = x + (size_t)b * CT_;
    f32x4 acc[4] = {{0.f,0.f,0.f,0.f},{0.f,0.f,0.f,0.f},
                    {0.f,0.f,0.f,0.f},{0.f,0.f,0.f,0.f}};
    int arow = w * 16 + (lane & 15);
    int koff = (lane >> 4) * 8;

    for (int cc0 = 0; cc0 < C_; cc0 += 64) {
#pragma unroll
        for (int q = 0; q < 4; ++q) {
            int idx = tid + q * 256;
            int er = idx >> 4, c4 = (idx & 15) * 4;
            float4 v = *(const float4*)(mw + (size_t)(e0 + er) * C_ + cc0 + c4);
            ushort4 h, l;
            h.x = f2bf(v.x); l.x = f2bf(v.x - bf2f(h.x));
            h.y = f2bf(v.y); l.y = f2bf(v.y - bf2f(h.y));
            h.z = f2bf(v.z); l.z = f2bf(v.z - bf2f(h.z));
            h.w = f2bf(v.w); l.w = f2bf(v.w - bf2f(h.w));
            *(ushort4*)&Ah[er][c4] = h;
            *(ushort4*)&Al[er][c4] = l;
        }
#pragma unroll
        for (int q = 0; q < 4; ++q) {
            int idx = tid + q * 256;
            int cr = idx >> 4, t4 = (idx & 15) * 4;
            float4 v = *(const float4*)(xb + (size_t)(cc0 + cr) * T_ + t0 + t4);
            float vv[4] = {v.x, v.y, v.z, v.w};
#pragma unroll
            for (int j = 0; j < 4; ++j) {
                ushort h = f2bf(vv[j]);
                Bh[t4 + j][cr] = h;
                Bl[t4 + j][cr] = f2bf(vv[j] - bf2f(h));
            }
        }
        __syncthreads();
#pragma unroll
        for (int ks = 0; ks < 2; ++ks) {
            int cb = ks * 32 + koff;
            bf16x8 ah = *(const bf16x8*)&Ah[arow][cb];
            bf16x8 al = *(const bf16x8*)&Al[arow][cb];
#pragma unroll
            for (int n = 0; n < 4; ++n) {
                int brow = n * 16 + (lane & 15);
                bf16x8 bh = *(const bf16x8*)&Bh[brow][cb];
                bf16x8 bl = *(const bf16x8*)&Bl[brow][cb];
                acc[n] = __builtin_amdgcn_mfma_f32_16x16x32_bf16(ah, bh, acc[n], 0, 0, 0);
                acc[n] = __builtin_amdgcn_mfma_f32_16x16x32_bf16(ah, bl, acc[n], 0, 0, 0);
                acc[n] = __builtin_amdgcn_mfma_f32_16x16x32_bf16(al, bh, acc[n], 0, 0, 0);
            }
        }
        __syncthreads();
    }
    float tau = tau0[b];
    float zs = 0.f;
#pragma unroll
    for (int n = 0; n < 4; ++n) {
        int t = t0 + n * 16 + (lane & 15);
        float rnv = rn[b * T_ + t];
#pragma unroll
        for (int r = 0; r < 4; ++r) {
            int e = e0 + w * 16 + (lane >> 4) * 4 + r;
            float v = acc[n][r] * rnv + mb[e];
            zs += __expf(v);
            if (v >= tau) {
                int pos = atomicAdd(&cnt[b], 1);
                if (pos < CAP_) {
                    cval[b * CAP_ + pos] = v;
                    cidx[b * CAP_ + pos] = e * T_ + t;
                }
            }
        }
    }
#pragma unroll
    for (int off = 32; off; off >>= 1) zs += __shfl_xor(zs, off, 64);
    if (lane == 0) red[w] = zs;
    __syncthreads();
    if (tid == 0) atomicAdd(&Z[b], (red[0] + red[1]) + (red[2] + red[3]));
}

// exact top-K selection among candidates (value desc, index asc on ties)
__launch_bounds__(256)
__global__ void k_select(const float* __restrict__ cval, const int* __restrict__ cidx,
                         const int* __restrict__ cnt, const float* __restrict__ Z,
                         int* __restrict__ sel_e, int* __restrict__ sel_t,
                         float* __restrict__ sel_sp) {
    __shared__ int h[NB2_];
    __shared__ int part[256];
    __shared__ float bl_v[1024];
    __shared__ int bl_i[1024];
    __shared__ int nb, bstar, nabove, outcnt;
    int b = blockIdx.x, tid = threadIdx.x;
    int n = cnt[b]; if (n > CAP_) n = CAP_;
    for (int i = tid; i < NB2_; i += 256) h[i] = 0;
    if (tid == 0) { nb = 0; outcnt = 0; }
    __syncthreads();
    const float* vp = cval + b * CAP_;
    const int* ip = cidx + b * CAP_;
    for (int j = tid; j < n; j += 256) {
        int bin = (int)(vp[j] * ((float)NB2_ * 2.0f));   // [0,0.5) range
        bin = bin < 0 ? 0 : (bin > NB2_ - 1 ? NB2_ - 1 : bin);
        atomicAdd(&h[bin], 1);
    }
    __syncthreads();
    int ps = 0;
    for (int j = 0; j < 16; ++j) ps += h[tid * 16 + j];
    part[tid] = ps;
    __syncthreads();
    if (tid == 0) {
        int cum = 0, bs = 0, na = 0;
        for (int i = 255; i >= 0; --i) {
            if (cum + part[i] >= K_) {
                int cum2 = cum;
                for (int j = 15; j >= 0; --j) {
                    cum2 += h[i * 16 + j];
                    if (cum2 >= K_) { bs = i * 16 + j; na = cum2 - h[i * 16 + j]; break; }
                }
                break;
            }
            cum += part[i];
        }
        bstar = bs; nabove = na;
    }
    __syncthreads();
    int bs = bstar;
    for (int j = tid; j < n; j += 256) {
        float v = vp[j];
        int bin = (int)(v * ((float)NB2_ * 2.0f));
        bin = bin < 0 ? 0 : (bin > NB2_ - 1 ? NB2_ - 1 : bin);
        if (bin == bs) {
            int q = atomicAdd(&nb, 1);
            if (q < 1024) { bl_v[q] = v; bl_i[q] = ip[j]; }
        }
    }
    __syncthreads();
    float rZ = 1.0f / Z[b];
    for (int j = tid; j < n; j += 256) {
        float v = vp[j];
        int bin = (int)(v * ((float)NB2_ * 2.0f));
        bin = bin < 0 ? 0 : (bin > NB2_ - 1 ? NB2_ - 1 : bin);
        if (bin > bs) {
            int q = atomicAdd(&outcnt, 1);
            int idx = ip[j];
            sel_e[b * K_ + q] = idx / T_;
            sel_t[b * K_ + q] = idx % T_;
            sel_sp[b * K_ + q] = __expf(v) * rZ;
        }
    }
    __syncthreads();
    if (tid == 0) {
        int m = nb; if (m > 1024) m = 1024;
        for (int i = 1; i < m; ++i) {          // insertion sort: val desc, idx asc
            float v = bl_v[i]; int id = bl_i[i]; int j = i - 1;
            while (j >= 0 && (bl_v[j] < v || (bl_v[j] == v && bl_i[j] > id))) {
                bl_v[j + 1] = bl_v[j]; bl_i[j + 1] = bl_i[j]; --j;
            }
            bl_v[j + 1] = v; bl_i[j + 1] = id;
        }
        int need = K_ - nabove;
        for (int q = 0; q < need; ++q) {
            int slot = nabove + q;
            if (q < m) {
                int idx = bl_i[q];
                sel_e[b * K_ + slot] = idx / T_;
                sel_t[b * K_ + slot] = idx % T_;
                sel_sp[b * K_ + slot] = __expf(bl_v[q]) * rZ;
            } else {  // pathological fallback: harmless zero entries
                sel_e[b * K_ + slot] = 0; sel_t[b * K_ + slot] = 0;
                sel_sp[b * K_ + slot] = 0.f;
            }
        }
    }
}

// up at selected positions via tiled split-x
__global__ void k_upg2(const ushort* __restrict__ xh, const ushort* __restrict__ xl,
                       const float* __restrict__ nrm, const float* __restrict__ uw,
                       const float* __restrict__ ub, const int* __restrict__ sel_e,
                       const int* __restrict__ sel_t, const float* __restrict__ sel_sp,
                       float* __restrict__ gval) {
    int gid = blockIdx.x * 256 + threadIdx.x;   // B*K waves
    int w = gid >> 6, lane = gid & 63;
    int b = w >> 9, i = w & (K_ - 1);
    int e = sel_e[b * K_ + i], t = sel_t[b * K_ + i];
    int ttile = t >> 6, trow = t & 63;
    int cc = lane >> 4, cb = (lane >> 1) & 7, half = lane & 1;
    size_t ro = ((((size_t)b * 128 + ttile) * 4 + cc) * 8 + cb) * 512
              + (size_t)trow * 8 + half * 4;          // c = lane*4 .. +4
    ushort4 h = *(const ushort4*)(xh + ro);
    ushort4 l = *(const ushort4*)(xl + ro);
    float4 wv = *(const float4*)(uw + (size_t)e * C_ + lane * 4);
    float acc = (bf2f(h.x) + bf2f(l.x)) * wv.x + (bf2f(h.y) + bf2f(l.y)) * wv.y
              + (bf2f(h.z) + bf2f(l.z)) * wv.z + (bf2f(h.w) + bf2f(l.w)) * wv.w;
#pragma unroll
    for (int off = 32; off; off >>= 1) acc += __shfl_down(acc, off, 64);
    if (lane == 0)
        gval[b * K_ + i] = sel_sp[b * K_ + i] * (acc * nrm[b * T_ + t] + ub[e]);
}

// fallback k_upg (raw x, strided)
__global__ void k_upg(const float* __restrict__ x, const float* __restrict__ uw,
                      const float* __restrict__ ub, const int* __restrict__ sel_e,
                      const int* __restrict__ sel_t, const float* __restrict__ sel_sp,
                      float* __restrict__ gval) {
    int gid = blockIdx.x * 256 + threadIdx.x;   // B*K waves
    int w = gid >> 6, lane = gid & 63;
    int b = w >> 9, i = w & (K_ - 1);
    int e = sel_e[b * K_ + i], t = sel_t[b * K_ + i];
    const float* xp = x + (size_t)b * CT_ + t;
    const float* wp = uw + (size_t)e * C_;
    float acc = 0.f;
    for (int c = lane; c < C_; c += 64) acc += wp[c] * xp[(size_t)c * T_];
    for (int off = 32; off; off >>= 1) acc += __shfl_down(acc, off, 64);
    if (lane == 0) gval[b * K_ + i] = sel_sp[b * K_ + i] * (acc + ub[e]);
}

// merged base + S1/Q: one wave per (b,c)
__global__ void k_bsq(const float* __restrict__ sw, const float* __restrict__ sb,
                      const float* __restrict__ db, const float* __restrict__ dw,
                      const int* __restrict__ sel_e, const float* __restrict__ gval,
                      float* __restrict__ base, float* __restrict__ S1,
                      float* __restrict__ Qv) {
    int wg = blockIdx.x * 4 + (threadIdx.x >> 6);   // 2048 waves
    int lane = threadIdx.x & 63;
    int b = wg >> 8, c = wg & (C_ - 1);
    float p = 0.f, s = 0.f, q = 0.f;
    for (int i = lane; i < K_; i += 64) {
        int e = sel_e[b * K_ + i];
        float g = gval[b * K_ + i];
        p += g * sw[(size_t)c * E_ + e];
        float wv = dw[(size_t)c * E_ + e] * g;
        s += wv; q += wv * wv;
    }
#pragma unroll
    for (int off = 32; off; off >>= 1) {
        p += __shfl_xor(p, off, 64);
        s += __shfl_xor(s, off, 64);
        q += __shfl_xor(q, off, 64);
    }
    if (lane == 0) {
        base[b * C_ + c] = p + sb[c] + db[c];
        S1[b * C_ + c] = s; Qv[b * C_ + c] = q;
    }
}

// BN stats analytic
__global__ void k_bnstats(const float* __restrict__ base, const float* __restrict__ S1,
                          const float* __restrict__ Qv, const float* __restrict__ bnw,
                          const float* __restrict__ bnb, float* __restrict__ scalec,
                          float* __restrict__ obase) {
    int c = threadIdx.x;
    float msum = 0.f;
    for (int b = 0; b < B_; ++b) msum += (float)T_ * base[b * C_ + c] + S1[b * C_ + c];
    float mean = msum / (float)(B_ * T_);
    float vs = 0.f;
    for (int b = 0; b < B_; ++b) {
        float d = base[b * C_ + c] - mean;
        vs += (float)T_ * d * d + 2.0f * d * S1[b * C_ + c] + Qv[b * C_ + c];
    }
    float var = vs / (float)(B_ * T_);
    float sc = bnw[c] * rsqrtf(var + 1e-5f);
    scalec[c] = sc;
    for (int b = 0; b < B_; ++b)
        obase[b * C_ + c] = (base[b * C_ + c] - mean) * sc + bnb[c];
}

// fill output with column-constant base
__global__ void k_fill(const float* __restrict__ obase, float* __restrict__ out) {
    size_t gid = (size_t)blockIdx.x * 256 + threadIdx.x;
    size_t flat = gid * 4;
    int b = (int)(flat / CT_);
    int c = (int)(flat / T_) & (C_ - 1);
    float v = obase[b * C_ + c];
    float4 o = {v, v, v, v};
    *(float4*)(out + flat) = o;
}

// add spikes
__global__ void k_spikes(const float* __restrict__ dw, const float* __restrict__ scalec,
                         const int* __restrict__ sel_e, const int* __restrict__ sel_t,
                         const float* __restrict__ gval, float* __restrict__ out) {
    int gid = blockIdx.x * 256 + threadIdx.x;   // B*K*64 threads
    int s = gid >> 6, cq = (gid & 63) * 4;
    int b = s >> 9, i = s & (K_ - 1);
    int e = sel_e[b * K_ + i], t = sel_t[b * K_ + i];
    float g = gval[b * K_ + i];
#pragma unroll
    for (int q = 0; q < 4; ++q) {
        int c = cq + q;
        atomicAdd(out + (size_t)b * CT_ + (size_t)c * T_ + t,
                  scalec[c] * dw[(size_t)c * E_ + e] * g);
    }
}

extern "C" void kernel_launch(void* const* d_in, const int* in_sizes, int n_in,
                              void* d_out, int out_size, void* d_ws, size_t ws_size,
                              hipStream_t stream) {
    const float* x = (const float*)d_in[0];
    const float* up_w = (const float*)d_in[1];
    const float* up_b = (const float*)d_in[2];
    const float* mask_w = (const float*)d_in[3];
    const float* mask_b = (const float*)d_in[4];
    const float* sum_w = (const float*)d_in[5];
    const float* sum_b = (const float*)d_in[6];
    const float* down_w = (const float*)d_in[7];
    const float* down_b = (const float*)d_in[8];
    const float* bn_w = (const float*)d_in[9];
    const float* bn_b = (const float*)d_in[10];
    float* out = (float*)d_out;

    // workspace layout (float units)
    float* ws = (float*)d_ws;
    size_t o = 0;
    float* rn = ws + o;   o += (size_t)B_ * T_;
    float* nrm = ws + o;  o += (size_t)B_ * T_;
    float* xs = ws + o;   o += (size_t)B_ * C_ * SCOLS_;
    float* msub = ws + o; o += (size_t)B_ * SUBN_;
    float* tau0 = ws + o; o += B_;
    float* Z = ws + o;    o += B_;
    int* cnt = (int*)(ws + o);   o += B_;
    float* cval = ws + o; o += (size_t)B_ * CAP_;
    int* cidx = (int*)(ws + o);  o += (size_t)B_ * CAP_;
    int* sel_e = (int*)(ws + o); o += (size_t)B_ * K_;
    int* sel_t = (int*)(ws + o); o += (size_t)B_ * K_;
    float* sel_sp = ws + o; o += (size_t)B_ * K_;
    float* gval = ws + o;   o += (size_t)B_ * K_;
    float* base = ws + o;   o += (size_t)B_ * C_;
    float* S1 = ws + o;     o += (size_t)B_ * C_;
    float* Qv = ws + o;     o += (size_t)B_ * C_;
    float* scalec = ws + o; o += C_;
    float* obase = ws + o;  o += (size_t)B_ * C_ + 8;
    // no-atomic collection buffers
    float* zpart = ws + o;  o += NBLK_;
    int* cntB = (int*)(ws + o); o += NBLK_;
    float* cvalB = ws + o;  o += (size_t)NBLK_ * BCAP_;
    int* cidxB = (int*)(ws + o); o += (size_t)NBLK_ * BCAP_;
    int* ovc = (int*)(ws + o); o += B_;
    float* ovv = ws + o;    o += (size_t)B_ * OCAP_;
    int* ovi = (int*)(ws + o); o += (size_t)B_ * OCAP_;
    // big split buffers last
    ushort* mwh = (ushort*)(ws + o); o += (size_t)E_ * C_ / 2;
    ushort* mwl = (ushort*)(ws + o); o += (size_t)E_ * C_ / 2;
    ushort* xh = (ushort*)(ws + o);  o += (size_t)B_ * T_ * C_ / 2;
    ushort* xl = (ushort*)(ws + o);  o += (size_t)B_ * T_ * C_ / 2;
    bool fast = ws_size >= o * sizeof(float);

    k_rn<<<(B_ * T_) / 256, 256, 0, stream>>>(x, rn, nrm, Z, cnt, ovc);
    k_gather<<<(B_ * C_ * SCOLS_) / 256, 256, 0, stream>>>(x, rn, xs);
    k_msub2<<<dim3(SCOLS_ / 64, E_ / 64, B_), 256, 0, stream>>>(xs, mask_w, mask_b, msub);
    k_tau<<<B_, 256, 0, stream>>>(msub, tau0);
    if (fast) {
        k_split_w<<<(E_ * C_ / 8) / 256, 256, 0, stream>>>(mask_w, mwh, mwl);
        k_split_x<<<dim3(T_ / 64, C_ / 64, B_), 256, 0, stream>>>(x, rn, xh, xl);
        k_gemm128<<<NBLK_, 256, 0, stream>>>(mwh, mwl, xh, xl, mask_b, tau0,
                                             zpart, cntB, cvalB, cidxB,
                                             ovc, ovv, ovi);
        k_compact<<<B_, 256, 0, stream>>>(zpart, cntB, cvalB, cidxB,
                                          ovc, ovv, ovi, Z, cnt, cval, cidx);
    } else {
        k_gemm<<<dim3(T_ / 64, E_ / 64, B_), 256, 0, stream>>>(
            x, mask_w, mask_b, rn, tau0, Z, cnt, cval, cidx);
    }
    k_select<<<B_, 256, 0, stream>>>(cval, cidx, cnt, Z, sel_e, sel_t, sel_sp);
    if (fast) {
        k_upg2<<<(B_ * K_ * 64) / 256, 256, 0, stream>>>(xh, xl, nrm, up_w, up_b,
                                                         sel_e, sel_t, sel_sp, gval);
    } else {
        k_upg<<<(B_ * K_ * 64) / 256, 256, 0, stream>>>(x, up_w, up_b, sel_e, sel_t,
                                                        sel_sp, gval);
    }
    k_bsq<<<(B_ * C_) / 4, 256, 0, stream>>>(sum_w, sum_b, down_b, down_w,
                                             sel_e, gval, base, S1, Qv);
    k_bnstats<<<1, C_, 0, stream>>>(base, S1, Qv, bn_w, bn_b, scalec, obase);
    k_fill<<<(B_ * CT_ / 4) / 256, 256, 0, stream>>>(obase, out);
    k_spikes<<<(B_ * K_ * 64) / 256, 256, 0, stream>>>(down_w, scalec, sel_e, sel_t,
                                                       gval, out);
}

// Round 10
// 267.195 us; speedup vs baseline: 2.3827x; 1.2090x over previous
//
#include <hip/hip_runtime.h>
#include <hip/hip_bf16.h>

// Problem constants (fixed by the reference)
#define B_ 8
#define C_ 256
#define E_ 512
#define T_ 8192
#define K_ 512
#define CT_ (C_*T_)
#define CAP_ 32768          // compacted candidate capacity per batch
#define BCAP_ 512           // per-block LDS candidate capacity (expected ~20)
#define OCAP_ 1024          // per-batch overflow capacity
#define NBLK_ 2048          // k_gemm128 grid
#define SUBS_ 64            // t-subsample stride
#define SCOLS_ (T_/SUBS_)   // 128
#define SUBN_ (E_*SCOLS_)   // 65536 subsample points per batch
#define RANK_ 64            // subsample rank -> expected full count ~4096
#define NB1_ 4096           // subsample histogram bins over [-1,1)
#define NB2_ 4096           // selection histogram bins over [0,0.5)
#define TAUP_ 8             // histogram partial blocks per batch

typedef __attribute__((ext_vector_type(8))) short bf16x8;
typedef __attribute__((ext_vector_type(4))) float f32x4;

__device__ __forceinline__ ushort f2bf(float f) {
    __hip_bfloat16 h = __float2bfloat16(f);
    return *reinterpret_cast<ushort*>(&h);
}
__device__ __forceinline__ float bf2f(ushort u) {
    __hip_bfloat16 h = *reinterpret_cast<__hip_bfloat16*>(&u);
    return __bfloat162float(h);
}

// async global->LDS, 16B per lane; LDS dest = wave-uniform base + lane*16
__device__ __forceinline__ void gl16(const void* g, void* l) {
    __builtin_amdgcn_global_load_lds(
        (const __attribute__((address_space(1))) void*)g,
        (__attribute__((address_space(3))) void*)l, 16, 0, 0);
}

// Tiled operand layout (ushort units):
//   W tiles:  [etile(8)][cc(4)][cb(8)][erow(64)][8]   (16384 per etile)
//   X tiles:  [b*128+ttile][cc(4)][cb(8)][trow(64)][8] (16384 per ttile)

// rn/nrm; block 0 inits Z, cnt, ovc
__global__ void k_rn(const float* __restrict__ x, float* __restrict__ rn,
                     float* __restrict__ nrm, float* __restrict__ Z,
                     int* __restrict__ cnt, int* __restrict__ ovc) {
    if (blockIdx.x == 0 && threadIdx.x < B_) {
        Z[threadIdx.x] = 0.f; cnt[threadIdx.x] = 0; ovc[threadIdx.x] = 0;
    }
    int gid = blockIdx.x * 256 + threadIdx.x;   // B*T threads
    int b = gid / T_, t = gid % T_;
    const float* xp = x + (size_t)b * CT_ + t;
    float s0 = 0.f, s1 = 0.f, s2 = 0.f, s3 = 0.f;
    for (int c = 0; c < C_; c += 4) {
        float a0 = xp[(size_t)c * T_];
        float a1 = xp[(size_t)(c + 1) * T_];
        float a2 = xp[(size_t)(c + 2) * T_];
        float a3 = xp[(size_t)(c + 3) * T_];
        s0 += a0 * a0; s1 += a1 * a1; s2 += a2 * a2; s3 += a3 * a3;
    }
    float s = (s0 + s1) + (s2 + s3);
    float n = sqrtf(s) + 1e-8f;
    nrm[gid] = n;
    rn[gid] = 1.0f / n;
}

// split mask_w into bf16 hi/lo, TILED layout (coalesced 16B writes)
__global__ void k_split_w(const float* __restrict__ mw, ushort* __restrict__ mwh,
                          ushort* __restrict__ mwl) {
    int idx = blockIdx.x * 256 + threadIdx.x;   // E*C/8 = 16384 threads
    int erow = idx & 63;
    int cb = (idx >> 6) & 7;
    int cc = (idx >> 9) & 3;
    int etile = idx >> 11;
    int e = etile * 64 + erow;
    int c0 = cc * 64 + cb * 8;
    const float* src = mw + (size_t)e * C_ + c0;
    ushort4 h0, l0, h1, l1;
    float v;
    v = src[0]; h0.x = f2bf(v); l0.x = f2bf(v - bf2f(h0.x));
    v = src[1]; h0.y = f2bf(v); l0.y = f2bf(v - bf2f(h0.y));
    v = src[2]; h0.z = f2bf(v); l0.z = f2bf(v - bf2f(h0.z));
    v = src[3]; h0.w = f2bf(v); l0.w = f2bf(v - bf2f(h0.w));
    v = src[4]; h1.x = f2bf(v); l1.x = f2bf(v - bf2f(h1.x));
    v = src[5]; h1.y = f2bf(v); l1.y = f2bf(v - bf2f(h1.y));
    v = src[6]; h1.z = f2bf(v); l1.z = f2bf(v - bf2f(h1.z));
    v = src[7]; h1.w = f2bf(v); l1.w = f2bf(v - bf2f(h1.w));
    *(ushort4*)(mwh + (size_t)idx * 8) = h0;
    *(ushort4*)(mwh + (size_t)idx * 8 + 4) = h1;
    *(ushort4*)(mwl + (size_t)idx * 8) = l0;
    *(ushort4*)(mwl + (size_t)idx * 8 + 4) = l1;
}

// transpose + rn-scale + split into TILED layout
__launch_bounds__(256)
__global__ void k_split_x(const float* __restrict__ x, const float* __restrict__ rn,
                          ushort* __restrict__ xh, ushort* __restrict__ xl) {
    __shared__ float tile[64][76];
    __shared__ float rnv[64];
    int tid = threadIdx.x;
    int ttile = blockIdx.x, cc = blockIdx.y, b = blockIdx.z;
    int t0 = ttile * 64, c0 = cc * 64;
    if (tid < 64) rnv[tid] = rn[b * T_ + t0 + tid];
    const float* xb = x + (size_t)b * CT_;
#pragma unroll
    for (int q = 0; q < 4; ++q) {
        int idx = tid + q * 256;
        int cr = idx >> 4, t4 = (idx & 15) * 4;
        float4 v = *(const float4*)(xb + (size_t)(c0 + cr) * T_ + t0 + t4);
        *(float4*)&tile[cr][t4] = v;
    }
    __syncthreads();
    size_t obase = (((size_t)b * 128 + ttile) * 4 + cc) * 4096;
#pragma unroll
    for (int q = 0; q < 4; ++q) {
        int idx = tid + q * 256;
        int tr = idx >> 4, c4 = (idx & 15) * 4;
        float s = rnv[tr];
        float v0 = tile[c4 + 0][tr] * s;
        float v1 = tile[c4 + 1][tr] * s;
        float v2 = tile[c4 + 2][tr] * s;
        float v3 = tile[c4 + 3][tr] * s;
        ushort4 h, l;
        h.x = f2bf(v0); l.x = f2bf(v0 - bf2f(h.x));
        h.y = f2bf(v1); l.y = f2bf(v1 - bf2f(h.y));
        h.z = f2bf(v2); l.z = f2bf(v2 - bf2f(h.z));
        h.w = f2bf(v3); l.w = f2bf(v3 - bf2f(h.w));
        int cb = c4 >> 3, half = (c4 >> 2) & 1;
        size_t ro = obase + (size_t)cb * 512 + tr * 8 + half * 4;
        *(ushort4*)(xh + ro) = h;
        *(ushort4*)(xl + ro) = l;
    }
}

// gather subsampled, rn-scaled x; first 32K threads also zero gh
__global__ void k_gather(const float* __restrict__ x, const float* __restrict__ rn,
                         float* __restrict__ xs, int* __restrict__ gh) {
    int gid = blockIdx.x * 256 + threadIdx.x;   // B*C*SCOLS threads = 262144
    if (gid < B_ * NB1_) gh[gid] = 0;
    int s = gid & (SCOLS_ - 1);
    int c = (gid >> 7) & (C_ - 1);
    int b = gid >> 15;
    int t = s * SUBS_;
    xs[gid] = x[(size_t)b * CT_ + (size_t)c * T_ + t] * rn[b * T_ + t];
}

// tiled f32 GEMM on compact gathered buffer (small: ~270 MFLOP)
__launch_bounds__(256)
__global__ void k_msub2(const float* __restrict__ xs, const float* __restrict__ mw,
                        const float* __restrict__ mb, float* __restrict__ msub) {
    __shared__ float As[64][68];
    __shared__ float Bs[64][68];
    int tid = threadIdx.x;
    int tx = tid & 15, ty = tid >> 4;
    int s0 = blockIdx.x * 64, e0 = blockIdx.y * 64, b = blockIdx.z;
    const float* xb = xs + (size_t)b * C_ * SCOLS_;
    float acc[4][4] = {};
    for (int c0 = 0; c0 < C_; c0 += 64) {
#pragma unroll
        for (int r = 0; r < 4; ++r) {
            int i = (tid >> 4) + r * 16;
            int kq = (tid & 15) * 4;
            float4 av = *(const float4*)(mw + (size_t)(e0 + i) * C_ + c0 + kq);
            As[kq + 0][i] = av.x; As[kq + 1][i] = av.y;
            As[kq + 2][i] = av.z; As[kq + 3][i] = av.w;
        }
#pragma unroll
        for (int r = 0; r < 4; ++r) {
            int k = (tid >> 4) + r * 16;
            int jq = (tid & 15) * 4;
            *(float4*)(&Bs[k][jq]) =
                *(const float4*)(xb + (size_t)(c0 + k) * SCOLS_ + s0 + jq);
        }
        __syncthreads();
#pragma unroll
        for (int k = 0; k < 64; ++k) {
            float4 a = *(const float4*)(&As[k][ty * 4]);
            float4 bq = *(const float4*)(&Bs[k][tx * 4]);
            float av[4] = {a.x, a.y, a.z, a.w};
            float bv[4] = {bq.x, bq.y, bq.z, bq.w};
#pragma unroll
            for (int ii = 0; ii < 4; ++ii)
#pragma unroll
                for (int jj = 0; jj < 4; ++jj)
                    acc[ii][jj] += av[ii] * bv[jj];
        }
        __syncthreads();
    }
#pragma unroll
    for (int ii = 0; ii < 4; ++ii) {
        float mbv = mb[e0 + ty * 4 + ii];
#pragma unroll
        for (int jj = 0; jj < 4; ++jj) {
            int e = e0 + ty * 4 + ii, s = s0 + tx * 4 + jj;
            msub[(size_t)b * SUBN_ + e * SCOLS_ + s] = acc[ii][jj] + mbv;
        }
    }
}

// parallel histogram of msub: 64 blocks (8 per batch) -> global gh[b][NB1]
__launch_bounds__(256)
__global__ void k_tau_hist(const float* __restrict__ msub, int* __restrict__ gh) {
    __shared__ int h[NB1_];
    int tid = threadIdx.x;
    int b = blockIdx.x >> 3, part = blockIdx.x & (TAUP_ - 1);
    for (int i = tid; i < NB1_; i += 256) h[i] = 0;
    __syncthreads();
    const float* mp = msub + (size_t)b * SUBN_ + part * (SUBN_ / TAUP_);
    for (int j = tid; j < SUBN_ / TAUP_; j += 256) {
        float v = mp[j];
        int bin = (int)((v + 1.0f) * ((float)NB1_ * 0.5f));
        bin = bin < 0 ? 0 : (bin > NB1_ - 1 ? NB1_ - 1 : bin);
        atomicAdd(&h[bin], 1);
    }
    __syncthreads();
    int* ghb = gh + b * NB1_;
    for (int i = tid; i < NB1_; i += 256)
        if (h[i]) atomicAdd(&ghb[i], h[i]);   // fire-and-forget, low contention
}

// per-batch conservative threshold tau0 from global histogram rank-64
__global__ void k_tau2(const int* __restrict__ gh, float* __restrict__ tau0) {
    __shared__ int part[256];
    int b = blockIdx.x, tid = threadIdx.x;
    const int* h = gh + b * NB1_;
    int ps = 0;
    for (int j = 0; j < 16; ++j) ps += h[tid * 16 + j];
    part[tid] = ps;
    __syncthreads();
    if (tid == 0) {
        int cum = 0, bf = 0;
        for (int i = 255; i >= 0; --i) {
            if (cum + part[i] >= RANK_) {
                int cum2 = cum;
                for (int j = 15; j >= 0; --j) {
                    cum2 += h[i * 16 + j];
                    if (cum2 >= RANK_) { bf = i * 16 + j; break; }
                }
                break;
            }
            cum += part[i];
        }
        tau0[b] = (float)bf * (2.0f / (float)NB1_) - 1.0f;  // bin lower edge
    }
}

// ---------------- fast main GEMM: 128x128 tile, NO global atomics -----------
// R7-proven K-loop verbatim. Epilogue: candidates -> LDS (shared count +
// 512-slot buffer, plain-store flush to per-block region); Z partial ->
// plain store. Global atomics only on (rare) per-block overflow.
__launch_bounds__(256)
__global__ void k_gemm128(const ushort* __restrict__ mwh, const ushort* __restrict__ mwl,
                          const ushort* __restrict__ xh, const ushort* __restrict__ xl,
                          const float* __restrict__ mb, const float* __restrict__ tau0,
                          float* __restrict__ zpart, int* __restrict__ cntB,
                          float* __restrict__ cvalB, int* __restrict__ cidxB,
                          int* __restrict__ ovc, float* __restrict__ ovv,
                          int* __restrict__ ovi) {
    __shared__ ushort S[8][4096];   // Wh0,Wh1,Wl0,Wl1,Xh0,Xh1,Xl0,Xl1 (8KB each)
    __shared__ float red[4];
    __shared__ float sval[BCAP_];
    __shared__ int sidx[BCAP_];
    __shared__ int scnt;
    int tid = threadIdx.x, lane = tid & 63, w = tid >> 6;
    int f = blockIdx.x;
    int xcd = f & 7, slot = f >> 3;          // XCD grouping: b == xcd
    int eblk = slot & 3, xt = slot >> 2;     // 4 e-blocks adjacent per x-tile
    int xtile = xcd * 64 + xt;               // 0..511 = b*64 + tt
    int b = xtile >> 6, tt = xtile & 63;
    int e0 = eblk * 128, t0 = tt * 128;
    if (tid == 0) scnt = 0;

    // wave w stages segments 2w and 2w+1 (8 gl16 each per chunk)
    int s0i = w * 2;
    const ushort* segp[2];
#pragma unroll
    for (int j = 0; j < 2; ++j) {
        int s = s0i + j;
        int hl = s & 1;
        const ushort* base;
        if (s < 2)      base = mwh + (size_t)(eblk * 2 + hl) * 16384;
        else if (s < 4) base = mwl + (size_t)(eblk * 2 + hl) * 16384;
        else if (s < 6) base = xh + ((size_t)b * 128 + tt * 2 + hl) * 16384;
        else            base = xl + ((size_t)b * 128 + tt * 2 + hl) * 16384;
        segp[j] = base + lane * 8;
    }

    f32x4 acc[4][4];
#pragma unroll
    for (int m = 0; m < 4; ++m)
#pragma unroll
        for (int n = 0; n < 4; ++n)
            acc[m][n] = (f32x4){0.f, 0.f, 0.f, 0.f};

    int a15 = lane & 15;
    int khalf = lane >> 4;                   // 0..3
    int wr = w >> 1, wc = w & 1;             // wave's 64x64 quadrant

    for (int cc = 0; cc < 4; ++cc) {
#pragma unroll
        for (int j = 0; j < 2; ++j) {
            const ushort* sp = segp[j] + cc * 4096;
            ushort* lp = &S[s0i + j][0];
#pragma unroll
            for (int i = 0; i < 8; ++i)
                gl16(sp + i * 512, lp + i * 512);
        }
        __syncthreads();
#pragma unroll
        for (int ks = 0; ks < 2; ++ks) {
            int cb16 = ks * 4 + khalf;
            bf16x8 ah[4], al[4], bh[4], bl[4];
#pragma unroll
            for (int m = 0; m < 4; ++m) {
                int aoff = (cb16 * 64 + m * 16 + a15) * 16;
                ah[m] = *(const bf16x8*)((const char*)&S[wr][0] + aoff);
                al[m] = *(const bf16x8*)((const char*)&S[2 + wr][0] + aoff);
            }
#pragma unroll
            for (int n = 0; n < 4; ++n) {
                int boff = (cb16 * 64 + n * 16 + a15) * 16;
                bh[n] = *(const bf16x8*)((const char*)&S[4 + wc][0] + boff);
                bl[n] = *(const bf16x8*)((const char*)&S[6 + wc][0] + boff);
            }
#pragma unroll
            for (int m = 0; m < 4; ++m)
#pragma unroll
                for (int n = 0; n < 4; ++n) {
                    acc[m][n] = __builtin_amdgcn_mfma_f32_16x16x32_bf16(ah[m], bh[n], acc[m][n], 0, 0, 0);
                    acc[m][n] = __builtin_amdgcn_mfma_f32_16x16x32_bf16(ah[m], bl[n], acc[m][n], 0, 0, 0);
                    acc[m][n] = __builtin_amdgcn_mfma_f32_16x16x32_bf16(al[m], bh[n], acc[m][n], 0, 0, 0);
                }
        }
        __syncthreads();
    }

    // epilogue: C/D layout col(t)=lane&15, row(e)=(lane>>4)*4+reg
    float tau = tau0[b];
    float zs = 0.f;
    int erow0 = e0 + wr * 64 + (lane >> 4) * 4;
#pragma unroll
    for (int m = 0; m < 4; ++m)
#pragma unroll
        for (int r = 0; r < 4; ++r) {
            int e = erow0 + m * 16 + r;
            float mbe = mb[e];
#pragma unroll
            for (int n = 0; n < 4; ++n) {
                int t = t0 + wc * 64 + n * 16 + a15;
                float v = acc[m][n][r] + mbe;
                zs += __expf(v);
                if (v >= tau) {
                    int pos = atomicAdd(&scnt, 1);       // LDS atomic (fast)
                    if (pos < BCAP_) {
                        sval[pos] = v;
                        sidx[pos] = e * T_ + t;
                    } else {                             // rare overflow spill
                        int q = atomicAdd(&ovc[b], 1);
                        if (q < OCAP_) {
                            ovv[b * OCAP_ + q] = v;
                            ovi[b * OCAP_ + q] = e * T_ + t;
                        }
                    }
                }
            }
        }
#pragma unroll
    for (int off = 32; off; off >>= 1) zs += __shfl_xor(zs, off, 64);
    if (lane == 0) red[w] = zs;
    __syncthreads();
    // flush: plain stores only
    int nc = scnt < BCAP_ ? scnt : BCAP_;
    for (int j = tid; j < nc; j += 256) {
        cvalB[(size_t)f * BCAP_ + j] = sval[j];
        cidxB[(size_t)f * BCAP_ + j] = sidx[j];
    }
    if (tid == 0) {
        cntB[f] = nc;
        zpart[f] = (red[0] + red[1]) + (red[2] + red[3]);
    }
}

// compact per-block candidate regions into per-batch arrays; sum Z
__launch_bounds__(256)
__global__ void k_compact(const float* __restrict__ zpart, const int* __restrict__ cntB,
                          const float* __restrict__ cvalB, const int* __restrict__ cidxB,
                          const int* __restrict__ ovc, const float* __restrict__ ovv,
                          const int* __restrict__ ovi, float* __restrict__ Z,
                          int* __restrict__ cnt, float* __restrict__ cval,
                          int* __restrict__ cidx) {
    __shared__ int pre[256];
    __shared__ float zs[256];
    int b = blockIdx.x, tid = threadIdx.x;   // 256 threads, 256 regions/batch
    int f = b + 8 * tid;                     // region id (b == f&7 decode)
    int c = cntB[f];
    pre[tid] = c;
    zs[tid] = zpart[f];
    __syncthreads();
    // inclusive scan (Hillis-Steele) on pre
    for (int d = 1; d < 256; d <<= 1) {
        int v = (tid >= d) ? pre[tid - d] : 0;
        __syncthreads();
        pre[tid] += v;
        __syncthreads();
    }
    int start = pre[tid] - c;                // exclusive prefix
    int total = pre[255];
    for (int j = 0; j < c; ++j) {
        int d = start + j;
        if (d < CAP_) {
            cval[b * CAP_ + d] = cvalB[(size_t)f * BCAP_ + j];
            cidx[b * CAP_ + d] = cidxB[(size_t)f * BCAP_ + j];
        }
    }
    // Z reduction
    __syncthreads();
    for (int d = 128; d; d >>= 1) {
        if (tid < d) zs[tid] += zs[tid + d];
        __syncthreads();
    }
    // append overflow (usually 0)
    int no = ovc[b]; if (no > OCAP_) no = OCAP_;
    for (int j = tid; j < no; j += 256) {
        int d = total + j;
        if (d < CAP_) {
            cval[b * CAP_ + d] = ovv[b * OCAP_ + j];
            cidx[b * CAP_ + d] = ovi[b * OCAP_ + j];
        }
    }
    if (tid == 0) {
        int tot = total + no;
        cnt[b] = tot < CAP_ ? tot : CAP_;
        Z[b] = zs[0];
    }
}

// exact top-K selection among candidates (value desc, index asc on ties)
__launch_bounds__(256)
__global__ void k_select(const float* __restrict__ cval, const int* __restrict__ cidx,
                         const int* __restrict__ cnt, const float* __restrict__ Z,
                         int* __restrict__ sel_e, int* __restrict__ sel_t,
                         float* __restrict__ sel_sp) {
    __shared__ int h[NB2_];
    __shared__ int part[256];
    __shared__ float bl_v[1024];
    __shared__ int bl_i[1024];
    __shared__ int nb, bstar, nabove, outcnt;
    int b = blockIdx.x, tid = threadIdx.x;
    int n = cnt[b]; if (n > CAP_) n = CAP_;
    for (int i = tid; i < NB2_; i += 256) h[i] = 0;
    if (tid == 0) { nb = 0; outcnt = 0; }
    __syncthreads();
    const float* vp = cval + b * CAP_;
    const int* ip = cidx + b * CAP_;
    for (int j = tid; j < n; j += 256) {
        int bin = (int)(vp[j] * ((float)NB2_ * 2.0f));   // [0,0.5) range
        bin = bin < 0 ? 0 : (bin > NB2_ - 1 ? NB2_ - 1 : bin);
        atomicAdd(&h[bin], 1);
    }
    __syncthreads();
    int ps = 0;
    for (int j = 0; j < 16; ++j) ps += h[tid * 16 + j];
    part[tid] = ps;
    __syncthreads();
    if (tid == 0) {
        int cum = 0, bs = 0, na = 0;
        for (int i = 255; i >= 0; --i) {
            if (cum + part[i] >= K_) {
                int cum2 = cum;
                for (int j = 15; j >= 0; --j) {
                    cum2 += h[i * 16 + j];
                    if (cum2 >= K_) { bs = i * 16 + j; na = cum2 - h[i * 16 + j]; break; }
                }
                break;
            }
            cum += part[i];
        }
        bstar = bs; nabove = na;
    }
    __syncthreads();
    int bs = bstar;
    for (int j = tid; j < n; j += 256) {
        float v = vp[j];
        int bin = (int)(v * ((float)NB2_ * 2.0f));
        bin = bin < 0 ? 0 : (bin > NB2_ - 1 ? NB2_ - 1 : bin);
        if (bin == bs) {
            int q = atomicAdd(&nb, 1);
            if (q < 1024) { bl_v[q] = v; bl_i[q] = ip[j]; }
        }
    }
    __syncthreads();
    float rZ = 1.0f / Z[b];
    for (int j = tid; j < n; j += 256) {
        float v = vp[j];
        int bin = (int)(v * ((float)NB2_ * 2.0f));
        bin = bin < 0 ? 0 : (bin > NB2_ - 1 ? NB2_ - 1 : bin);
        if (bin > bs) {
            int q = atomicAdd(&outcnt, 1);
            int idx = ip[j];
            sel_e[b * K_ + q] = idx / T_;
            sel_t[b * K_ + q] = idx % T_;
            sel_sp[b * K_ + q] = __expf(v) * rZ;
        }
    }
    __syncthreads();
    if (tid == 0) {
        int m = nb; if (m > 1024) m = 1024;
        for (int i = 1; i < m; ++i) {          // insertion sort: val desc, idx asc
            float v = bl_v[i]; int id = bl_i[i]; int j = i - 1;
            while (j >= 0 && (bl_v[j] < v || (bl_v[j] == v && bl_i[j] > id))) {
                bl_v[j + 1] = bl_v[j]; bl_i[j + 1] = bl_i[j]; --j;
            }
            bl_v[j + 1] = v; bl_i[j + 1] = id;
        }
        int need = K_ - nabove;
        for (int q = 0; q < need; ++q) {
            int slot = nabove + q;
            if (q < m) {
                int idx = bl_i[q];
                sel_e[b * K_ + slot] = idx / T_;
                sel_t[b * K_ + slot] = idx % T_;
                sel_sp[b * K_ + slot] = __expf(bl_v[q]) * rZ;
            } else {  // pathological fallback: harmless zero entries
                sel_e[b * K_ + slot] = 0; sel_t[b * K_ + slot] = 0;
                sel_sp[b * K_ + slot] = 0.f;
            }
        }
    }
}

// up at selected positions via tiled split-x
__global__ void k_upg2(const ushort* __restrict__ xh, const ushort* __restrict__ xl,
                       const float* __restrict__ nrm, const float* __restrict__ uw,
                       const float* __restrict__ ub, const int* __restrict__ sel_e,
                       const int* __restrict__ sel_t, const float* __restrict__ sel_sp,
                       float* __restrict__ gval) {
    int gid = blockIdx.x * 256 + threadIdx.x;   // B*K waves
    int w = gid >> 6, lane = gid & 63;
    int b = w >> 9, i = w & (K_ - 1);
    int e = sel_e[b * K_ + i], t = sel_t[b * K_ + i];
    int ttile = t >> 6, trow = t & 63;
    int cc = lane >> 4, cb = (lane >> 1) & 7, half = lane & 1;
    size_t ro = ((((size_t)b * 128 + ttile) * 4 + cc) * 8 + cb) * 512
              + (size_t)trow * 8 + half * 4;          // c = lane*4 .. +4
    ushort4 h = *(const ushort4*)(xh + ro);
    ushort4 l = *(const ushort4*)(xl + ro);
    float4 wv = *(const float4*)(uw + (size_t)e * C_ + lane * 4);
    float acc = (bf2f(h.x) + bf2f(l.x)) * wv.x + (bf2f(h.y) + bf2f(l.y)) * wv.y
              + (bf2f(h.z) + bf2f(l.z)) * wv.z + (bf2f(h.w) + bf2f(l.w)) * wv.w;
#pragma unroll
    for (int off = 32; off; off >>= 1) acc += __shfl_down(acc, off, 64);
    if (lane == 0)
        gval[b * K_ + i] = sel_sp[b * K_ + i] * (acc * nrm[b * T_ + t] + ub[e]);
}

// merged base + S1/Q: one wave per (b,c)
__global__ void k_bsq(const float* __restrict__ sw, const float* __restrict__ sb,
                      const float* __restrict__ db, const float* __restrict__ dw,
                      const int* __restrict__ sel_e, const float* __restrict__ gval,
                      float* __restrict__ base, float* __restrict__ S1,
                      float* __restrict__ Qv) {
    int wg = blockIdx.x * 4 + (threadIdx.x >> 6);   // 2048 waves
    int lane = threadIdx.x & 63;
    int b = wg >> 8, c = wg & (C_ - 1);
    float p = 0.f, s = 0.f, q = 0.f;
    for (int i = lane; i < K_; i += 64) {
        int e = sel_e[b * K_ + i];
        float g = gval[b * K_ + i];
        p += g * sw[(size_t)c * E_ + e];
        float wv = dw[(size_t)c * E_ + e] * g;
        s += wv; q += wv * wv;
    }
#pragma unroll
    for (int off = 32; off; off >>= 1) {
        p += __shfl_xor(p, off, 64);
        s += __shfl_xor(s, off, 64);
        q += __shfl_xor(q, off, 64);
    }
    if (lane == 0) {
        base[b * C_ + c] = p + sb[c] + db[c];
        S1[b * C_ + c] = s; Qv[b * C_ + c] = q;
    }
}

// BN stats analytic
__global__ void k_bnstats(const float* __restrict__ base, const float* __restrict__ S1,
                          const float* __restrict__ Qv, const float* __restrict__ bnw,
                          const float* __restrict__ bnb, float* __restrict__ scalec,
                          float* __restrict__ obase) {
    int c = threadIdx.x;
    float msum = 0.f;
    for (int b = 0; b < B_; ++b) msum += (float)T_ * base[b * C_ + c] + S1[b * C_ + c];
    float mean = msum / (float)(B_ * T_);
    float vs = 0.f;
    for (int b = 0; b < B_; ++b) {
        float d = base[b * C_ + c] - mean;
        vs += (float)T_ * d * d + 2.0f * d * S1[b * C_ + c] + Qv[b * C_ + c];
    }
    float var = vs / (float)(B_ * T_);
    float sc = bnw[c] * rsqrtf(var + 1e-5f);
    scalec[c] = sc;
    for (int b = 0; b < B_; ++b)
        obase[b * C_ + c] = (base[b * C_ + c] - mean) * sc + bnb[c];
}

// fill output with column-constant base
__global__ void k_fill(const float* __restrict__ obase, float* __restrict__ out) {
    size_t gid = (size_t)blockIdx.x * 256 + threadIdx.x;
    size_t flat = gid * 4;
    int b = (int)(flat / CT_);
    int c = (int)(flat / T_) & (C_ - 1);
    float v = obase[b * C_ + c];
    float4 o = {v, v, v, v};
    *(float4*)(out + flat) = o;
}

// add spikes
__global__ void k_spikes(const float* __restrict__ dw, const float* __restrict__ scalec,
                         const int* __restrict__ sel_e, const int* __restrict__ sel_t,
                         const float* __restrict__ gval, float* __restrict__ out) {
    int gid = blockIdx.x * 256 + threadIdx.x;   // B*K*64 threads
    int s = gid >> 6, cq = (gid & 63) * 4;
    int b = s >> 9, i = s & (K_ - 1);
    int e = sel_e[b * K_ + i], t = sel_t[b * K_ + i];
    float g = gval[b * K_ + i];
#pragma unroll
    for (int q = 0; q < 4; ++q) {
        int c = cq + q;
        atomicAdd(out + (size_t)b * CT_ + (size_t)c * T_ + t,
                  scalec[c] * dw[(size_t)c * E_ + e] * g);
    }
}

extern "C" void kernel_launch(void* const* d_in, const int* in_sizes, int n_in,
                              void* d_out, int out_size, void* d_ws, size_t ws_size,
                              hipStream_t stream) {
    const float* x = (const float*)d_in[0];
    const float* up_w = (const float*)d_in[1];
    const float* up_b = (const float*)d_in[2];
    const float* mask_w = (const float*)d_in[3];
    const float* mask_b = (const float*)d_in[4];
    const float* sum_w = (const float*)d_in[5];
    const float* sum_b = (const float*)d_in[6];
    const float* down_w = (const float*)d_in[7];
    const float* down_b = (const float*)d_in[8];
    const float* bn_w = (const float*)d_in[9];
    const float* bn_b = (const float*)d_in[10];
    float* out = (float*)d_out;

    // workspace layout (float units)
    float* ws = (float*)d_ws;
    size_t o = 0;
    float* rn = ws + o;   o += (size_t)B_ * T_;
    float* nrm = ws + o;  o += (size_t)B_ * T_;
    float* xs = ws + o;   o += (size_t)B_ * C_ * SCOLS_;
    float* msub = ws + o; o += (size_t)B_ * SUBN_;
    float* tau0 = ws + o; o += B_;
    float* Z = ws + o;    o += B_;
    int* cnt = (int*)(ws + o);   o += B_;
    int* gh = (int*)(ws + o);    o += (size_t)B_ * NB1_;
    float* cval = ws + o; o += (size_t)B_ * CAP_;
    int* cidx = (int*)(ws + o);  o += (size_t)B_ * CAP_;
    int* sel_e = (int*)(ws + o); o += (size_t)B_ * K_;
    int* sel_t = (int*)(ws + o); o += (size_t)B_ * K_;
    float* sel_sp = ws + o; o += (size_t)B_ * K_;
    float* gval = ws + o;   o += (size_t)B_ * K_;
    float* base = ws + o;   o += (size_t)B_ * C_;
    float* S1 = ws + o;     o += (size_t)B_ * C_;
    float* Qv = ws + o;     o += (size_t)B_ * C_;
    float* scalec = ws + o; o += C_;
    float* obase = ws + o;  o += (size_t)B_ * C_ + 8;
    // no-atomic collection buffers
    float* zpart = ws + o;  o += NBLK_;
    int* cntB = (int*)(ws + o); o += NBLK_;
    float* cvalB = ws + o;  o += (size_t)NBLK_ * BCAP_;
    int* cidxB = (int*)(ws + o); o += (size_t)NBLK_ * BCAP_;
    int* ovc = (int*)(ws + o); o += B_;
    float* ovv = ws + o;    o += (size_t)B_ * OCAP_;
    int* ovi = (int*)(ws + o); o += (size_t)B_ * OCAP_;
    // big split buffers last
    ushort* mwh = (ushort*)(ws + o); o += (size_t)E_ * C_ / 2;
    ushort* mwl = (ushort*)(ws + o); o += (size_t)E_ * C_ / 2;
    ushort* xh = (ushort*)(ws + o);  o += (size_t)B_ * T_ * C_ / 2;
    ushort* xl = (ushort*)(ws + o);  o += (size_t)B_ * T_ * C_ / 2;
    (void)ws_size;

    k_rn<<<(B_ * T_) / 256, 256, 0, stream>>>(x, rn, nrm, Z, cnt, ovc);
    k_gather<<<(B_ * C_ * SCOLS_) / 256, 256, 0, stream>>>(x, rn, xs, gh);
    k_msub2<<<dim3(SCOLS_ / 64, E_ / 64, B_), 256, 0, stream>>>(xs, mask_w, mask_b, msub);
    k_tau_hist<<<B_ * TAUP_, 256, 0, stream>>>(msub, gh);
    k_tau2<<<B_, 256, 0, stream>>>(gh, tau0);
    k_split_w<<<(E_ * C_ / 8) / 256, 256, 0, stream>>>(mask_w, mwh, mwl);
    k_split_x<<<dim3(T_ / 64, C_ / 64, B_), 256, 0, stream>>>(x, rn, xh, xl);
    k_gemm128<<<NBLK_, 256, 0, stream>>>(mwh, mwl, xh, xl, mask_b, tau0,
                                         zpart, cntB, cvalB, cidxB,
                                         ovc, ovv, ovi);
    k_compact<<<B_, 256, 0, stream>>>(zpart, cntB, cvalB, cidxB,
                                      ovc, ovv, ovi, Z, cnt, cval, cidx);
    k_select<<<B_, 256, 0, stream>>>(cval, cidx, cnt, Z, sel_e, sel_t, sel_sp);
    k_upg2<<<(B_ * K_ * 64) / 256, 256, 0, stream>>>(xh, xl, nrm, up_w, up_b,
                                                     sel_e, sel_t, sel_sp, gval);
    k_bsq<<<(B_ * C_) / 4, 256, 0, stream>>>(sum_w, sum_b, down_b, down_w,
                                             sel_e, gval, base, S1, Qv);
    k_bnstats<<<1, C_, 0, stream>>>(base, S1, Qv, bn_w, bn_b, scalec, obase);
    k_fill<<<(B_ * CT_ / 4) / 256, 256, 0, stream>>>(obase, out);
    k_spikes<<<(B_ * K_ * 64) / 256, 256, 0, stream>>>(down_w, scalec, sel_e, sel_t,
                                                       gval, out);
}

// Round 11
// 265.173 us; speedup vs baseline: 2.4009x; 1.0076x over previous
//
#include <hip/hip_runtime.h>
#include <hip/hip_bf16.h>

// Problem constants (fixed by the reference)
#define B_ 8
#define C_ 256
#define E_ 512
#define T_ 8192
#define K_ 512
#define CT_ (C_*T_)
#define CAP_ 32768          // compacted candidate capacity per batch
#define BCAP_ 512           // per-block LDS candidate capacity (expected ~20)
#define OCAP_ 1024          // per-batch overflow capacity
#define NBLK_ 2048          // k_gemm128 grid
#define SUBS_ 64            // t-subsample stride
#define SCOLS_ (T_/SUBS_)   // 128
#define SUBN_ (E_*SCOLS_)   // 65536 subsample points per batch
#define RANK_ 64            // subsample rank -> expected full count ~4096
#define NB1_ 4096           // subsample histogram bins over [-1,1)
#define NB2_ 4096           // selection histogram bins over [0,0.5)
#define TAUP_ 8             // histogram partial blocks per batch

typedef __attribute__((ext_vector_type(8))) short bf16x8;
typedef __attribute__((ext_vector_type(4))) float f32x4;

__device__ __forceinline__ ushort f2bf(float f) {
    __hip_bfloat16 h = __float2bfloat16(f);
    return *reinterpret_cast<ushort*>(&h);
}
__device__ __forceinline__ float bf2f(ushort u) {
    __hip_bfloat16 h = *reinterpret_cast<__hip_bfloat16*>(&u);
    return __bfloat162float(h);
}

// async global->LDS, 16B per lane; LDS dest = wave-uniform base + lane*16
__device__ __forceinline__ void gl16(const void* g, void* l) {
    __builtin_amdgcn_global_load_lds(
        (const __attribute__((address_space(1))) void*)g,
        (__attribute__((address_space(3))) void*)l, 16, 0, 0);
}

// Tiled operand layout (ushort units):
//   W tiles:  [etile(8)][cc(4)][cb(8)][erow(64)][8]   (16384 per etile)
//   X tiles:  [b*128+ttile][cc(4)][cb(8)][trow(64)][8] (16384 per ttile)
// K-chunk of 32 (q=0..7) = contiguous 2048-ushort slab at q*2048.

// rn/nrm; block 0 inits ovc
__global__ void k_rn(const float* __restrict__ x, float* __restrict__ rn,
                     float* __restrict__ nrm, int* __restrict__ ovc) {
    if (blockIdx.x == 0 && threadIdx.x < B_) ovc[threadIdx.x] = 0;
    int gid = blockIdx.x * 256 + threadIdx.x;   // B*T threads
    int b = gid / T_, t = gid % T_;
    const float* xp = x + (size_t)b * CT_ + t;
    float s0 = 0.f, s1 = 0.f, s2 = 0.f, s3 = 0.f;
    for (int c = 0; c < C_; c += 4) {
        float a0 = xp[(size_t)c * T_];
        float a1 = xp[(size_t)(c + 1) * T_];
        float a2 = xp[(size_t)(c + 2) * T_];
        float a3 = xp[(size_t)(c + 3) * T_];
        s0 += a0 * a0; s1 += a1 * a1; s2 += a2 * a2; s3 += a3 * a3;
    }
    float s = (s0 + s1) + (s2 + s3);
    float n = sqrtf(s) + 1e-8f;
    nrm[gid] = n;
    rn[gid] = 1.0f / n;
}

// split mask_w into bf16 hi/lo, TILED layout (coalesced 16B writes)
__global__ void k_split_w(const float* __restrict__ mw, ushort* __restrict__ mwh,
                          ushort* __restrict__ mwl) {
    int idx = blockIdx.x * 256 + threadIdx.x;   // E*C/8 = 16384 threads
    int erow = idx & 63;
    int cb = (idx >> 6) & 7;
    int cc = (idx >> 9) & 3;
    int etile = idx >> 11;
    int e = etile * 64 + erow;
    int c0 = cc * 64 + cb * 8;
    const float* src = mw + (size_t)e * C_ + c0;
    ushort4 h0, l0, h1, l1;
    float v;
    v = src[0]; h0.x = f2bf(v); l0.x = f2bf(v - bf2f(h0.x));
    v = src[1]; h0.y = f2bf(v); l0.y = f2bf(v - bf2f(h0.y));
    v = src[2]; h0.z = f2bf(v); l0.z = f2bf(v - bf2f(h0.z));
    v = src[3]; h0.w = f2bf(v); l0.w = f2bf(v - bf2f(h0.w));
    v = src[4]; h1.x = f2bf(v); l1.x = f2bf(v - bf2f(h1.x));
    v = src[5]; h1.y = f2bf(v); l1.y = f2bf(v - bf2f(h1.y));
    v = src[6]; h1.z = f2bf(v); l1.z = f2bf(v - bf2f(h1.z));
    v = src[7]; h1.w = f2bf(v); l1.w = f2bf(v - bf2f(h1.w));
    *(ushort4*)(mwh + (size_t)idx * 8) = h0;
    *(ushort4*)(mwh + (size_t)idx * 8 + 4) = h1;
    *(ushort4*)(mwl + (size_t)idx * 8) = l0;
    *(ushort4*)(mwl + (size_t)idx * 8 + 4) = l1;
}

// transpose + rn-scale + split into TILED layout
__launch_bounds__(256)
__global__ void k_split_x(const float* __restrict__ x, const float* __restrict__ rn,
                          ushort* __restrict__ xh, ushort* __restrict__ xl) {
    __shared__ float tile[64][76];
    __shared__ float rnv[64];
    int tid = threadIdx.x;
    int ttile = blockIdx.x, cc = blockIdx.y, b = blockIdx.z;
    int t0 = ttile * 64, c0 = cc * 64;
    if (tid < 64) rnv[tid] = rn[b * T_ + t0 + tid];
    const float* xb = x + (size_t)b * CT_;
#pragma unroll
    for (int q = 0; q < 4; ++q) {
        int idx = tid + q * 256;
        int cr = idx >> 4, t4 = (idx & 15) * 4;
        float4 v = *(const float4*)(xb + (size_t)(c0 + cr) * T_ + t0 + t4);
        *(float4*)&tile[cr][t4] = v;
    }
    __syncthreads();
    size_t obase = (((size_t)b * 128 + ttile) * 4 + cc) * 4096;
#pragma unroll
    for (int q = 0; q < 4; ++q) {
        int idx = tid + q * 256;
        int tr = idx >> 4, c4 = (idx & 15) * 4;
        float s = rnv[tr];
        float v0 = tile[c4 + 0][tr] * s;
        float v1 = tile[c4 + 1][tr] * s;
        float v2 = tile[c4 + 2][tr] * s;
        float v3 = tile[c4 + 3][tr] * s;
        ushort4 h, l;
        h.x = f2bf(v0); l.x = f2bf(v0 - bf2f(h.x));
        h.y = f2bf(v1); l.y = f2bf(v1 - bf2f(h.y));
        h.z = f2bf(v2); l.z = f2bf(v2 - bf2f(h.z));
        h.w = f2bf(v3); l.w = f2bf(v3 - bf2f(h.w));
        int cb = c4 >> 3, half = (c4 >> 2) & 1;
        size_t ro = obase + (size_t)cb * 512 + tr * 8 + half * 4;
        *(ushort4*)(xh + ro) = h;
        *(ushort4*)(xl + ro) = l;
    }
}

// gather subsampled, rn-scaled x; first 32K threads also zero gh
__global__ void k_gather(const float* __restrict__ x, const float* __restrict__ rn,
                         float* __restrict__ xs, int* __restrict__ gh) {
    int gid = blockIdx.x * 256 + threadIdx.x;   // B*C*SCOLS threads = 262144
    if (gid < B_ * NB1_) gh[gid] = 0;
    int s = gid & (SCOLS_ - 1);
    int c = (gid >> 7) & (C_ - 1);
    int b = gid >> 15;
    int t = s * SUBS_;
    xs[gid] = x[(size_t)b * CT_ + (size_t)c * T_ + t] * rn[b * T_ + t];
}

// tiled f32 GEMM on compact gathered buffer (small: ~270 MFLOP)
__launch_bounds__(256)
__global__ void k_msub2(const float* __restrict__ xs, const float* __restrict__ mw,
                        const float* __restrict__ mb, float* __restrict__ msub) {
    __shared__ float As[64][68];
    __shared__ float Bs[64][68];
    int tid = threadIdx.x;
    int tx = tid & 15, ty = tid >> 4;
    int s0 = blockIdx.x * 64, e0 = blockIdx.y * 64, b = blockIdx.z;
    const float* xb = xs + (size_t)b * C_ * SCOLS_;
    float acc[4][4] = {};
    for (int c0 = 0; c0 < C_; c0 += 64) {
#pragma unroll
        for (int r = 0; r < 4; ++r) {
            int i = (tid >> 4) + r * 16;
            int kq = (tid & 15) * 4;
            float4 av = *(const float4*)(mw + (size_t)(e0 + i) * C_ + c0 + kq);
            As[kq + 0][i] = av.x; As[kq + 1][i] = av.y;
            As[kq + 2][i] = av.z; As[kq + 3][i] = av.w;
        }
#pragma unroll
        for (int r = 0; r < 4; ++r) {
            int k = (tid >> 4) + r * 16;
            int jq = (tid & 15) * 4;
            *(float4*)(&Bs[k][jq]) =
                *(const float4*)(xb + (size_t)(c0 + k) * SCOLS_ + s0 + jq);
        }
        __syncthreads();
#pragma unroll
        for (int k = 0; k < 64; ++k) {
            float4 a = *(const float4*)(&As[k][ty * 4]);
            float4 bq = *(const float4*)(&Bs[k][tx * 4]);
            float av[4] = {a.x, a.y, a.z, a.w};
            float bv[4] = {bq.x, bq.y, bq.z, bq.w};
#pragma unroll
            for (int ii = 0; ii < 4; ++ii)
#pragma unroll
                for (int jj = 0; jj < 4; ++jj)
                    acc[ii][jj] += av[ii] * bv[jj];
        }
        __syncthreads();
    }
#pragma unroll
    for (int ii = 0; ii < 4; ++ii) {
        float mbv = mb[e0 + ty * 4 + ii];
#pragma unroll
        for (int jj = 0; jj < 4; ++jj) {
            int e = e0 + ty * 4 + ii, s = s0 + tx * 4 + jj;
            msub[(size_t)b * SUBN_ + e * SCOLS_ + s] = acc[ii][jj] + mbv;
        }
    }
}

// parallel histogram of msub: 64 blocks (8 per batch) -> global gh[b][NB1]
__launch_bounds__(256)
__global__ void k_tau_hist(const float* __restrict__ msub, int* __restrict__ gh) {
    __shared__ int h[NB1_];
    int tid = threadIdx.x;
    int b = blockIdx.x >> 3, part = blockIdx.x & (TAUP_ - 1);
    for (int i = tid; i < NB1_; i += 256) h[i] = 0;
    __syncthreads();
    const float* mp = msub + (size_t)b * SUBN_ + part * (SUBN_ / TAUP_);
    for (int j = tid; j < SUBN_ / TAUP_; j += 256) {
        float v = mp[j];
        int bin = (int)((v + 1.0f) * ((float)NB1_ * 0.5f));
        bin = bin < 0 ? 0 : (bin > NB1_ - 1 ? NB1_ - 1 : bin);
        atomicAdd(&h[bin], 1);
    }
    __syncthreads();
    int* ghb = gh + b * NB1_;
    for (int i = tid; i < NB1_; i += 256)
        if (h[i]) atomicAdd(&ghb[i], h[i]);   // fire-and-forget, low contention
}

// per-batch conservative threshold tau0 from global histogram rank-64
__global__ void k_tau2(const int* __restrict__ gh, float* __restrict__ tau0) {
    __shared__ int part[256];
    int b = blockIdx.x, tid = threadIdx.x;
    const int* h = gh + b * NB1_;
    int ps = 0;
    for (int j = 0; j < 16; ++j) ps += h[tid * 16 + j];
    part[tid] = ps;
    __syncthreads();
    if (tid == 0) {
        int cum = 0, bf = 0;
        for (int i = 255; i >= 0; --i) {
            if (cum + part[i] >= RANK_) {
                int cum2 = cum;
                for (int j = 15; j >= 0; --j) {
                    cum2 += h[i * 16 + j];
                    if (cum2 >= RANK_) { bf = i * 16 + j; break; }
                }
                break;
            }
            cum += part[i];
        }
        tau0[b] = (float)bf * (2.0f / (float)NB1_) - 1.0f;  // bin lower edge
    }
}

// ---------------- fast main GEMM: 128x128 tile, K-chunk=32, 36KB LDS --------
// Same proven single-buffer 2-barrier chunk structure, 8 chunks of K=32.
// 36KB LDS -> 4 blocks/CU (16 waves) so the per-chunk vmcnt drain overlaps
// with other resident blocks' compute. No global atomics (R8 epilogue).
__launch_bounds__(256)
__global__ void k_gemm128(const ushort* __restrict__ mwh, const ushort* __restrict__ mwl,
                          const ushort* __restrict__ xh, const ushort* __restrict__ xl,
                          const float* __restrict__ mb, const float* __restrict__ tau0,
                          float* __restrict__ zpart, int* __restrict__ cntB,
                          float* __restrict__ cvalB, int* __restrict__ cidxB,
                          int* __restrict__ ovc, float* __restrict__ ovv,
                          int* __restrict__ ovi) {
    __shared__ ushort S[8][2048];   // Wh0,Wh1,Wl0,Wl1,Xh0,Xh1,Xl0,Xl1 (4KB each)
    __shared__ float red[4];
    __shared__ float sval[BCAP_];
    __shared__ int sidx[BCAP_];
    __shared__ int scnt;
    int tid = threadIdx.x, lane = tid & 63, w = tid >> 6;
    int f = blockIdx.x;
    int xcd = f & 7, slot = f >> 3;          // XCD grouping: b == xcd
    int eblk = slot & 3, xt = slot >> 2;     // 4 e-blocks adjacent per x-tile
    int xtile = xcd * 64 + xt;               // 0..511 = b*64 + tt
    int b = xtile >> 6, tt = xtile & 63;
    int e0 = eblk * 128, t0 = tt * 128;
    if (tid == 0) scnt = 0;

    // wave w stages segments 2w and 2w+1 (4 gl16 each per chunk)
    int s0i = w * 2;
    const ushort* segp[2];
#pragma unroll
    for (int j = 0; j < 2; ++j) {
        int s = s0i + j;
        int hl = s & 1;
        const ushort* base;
        if (s < 2)      base = mwh + (size_t)(eblk * 2 + hl) * 16384;
        else if (s < 4) base = mwl + (size_t)(eblk * 2 + hl) * 16384;
        else if (s < 6) base = xh + ((size_t)b * 128 + tt * 2 + hl) * 16384;
        else            base = xl + ((size_t)b * 128 + tt * 2 + hl) * 16384;
        segp[j] = base + lane * 8;
    }

    f32x4 acc[4][4];
#pragma unroll
    for (int m = 0; m < 4; ++m)
#pragma unroll
        for (int n = 0; n < 4; ++n)
            acc[m][n] = (f32x4){0.f, 0.f, 0.f, 0.f};

    int a15 = lane & 15;
    int khalf = lane >> 4;                   // 0..3 = cb16 within K=32 chunk
    int wr = w >> 1, wc = w & 1;             // wave's 64x64 quadrant

    for (int q = 0; q < 8; ++q) {            // K-chunk of 32 = 2048-ushort slab
#pragma unroll
        for (int j = 0; j < 2; ++j) {
            const ushort* sp = segp[j] + q * 2048;
            ushort* lp = &S[s0i + j][0];
#pragma unroll
            for (int i = 0; i < 4; ++i)
                gl16(sp + i * 512, lp + i * 512);
        }
        __syncthreads();
        {
            bf16x8 ah[4], al[4], bh[4], bl[4];
#pragma unroll
            for (int m = 0; m < 4; ++m) {
                int aoff = (khalf * 64 + m * 16 + a15) * 16;
                ah[m] = *(const bf16x8*)((const char*)&S[wr][0] + aoff);
                al[m] = *(const bf16x8*)((const char*)&S[2 + wr][0] + aoff);
            }
#pragma unroll
            for (int n = 0; n < 4; ++n) {
                int boff = (khalf * 64 + n * 16 + a15) * 16;
                bh[n] = *(const bf16x8*)((const char*)&S[4 + wc][0] + boff);
                bl[n] = *(const bf16x8*)((const char*)&S[6 + wc][0] + boff);
            }
#pragma unroll
            for (int m = 0; m < 4; ++m)
#pragma unroll
                for (int n = 0; n < 4; ++n) {
                    acc[m][n] = __builtin_amdgcn_mfma_f32_16x16x32_bf16(ah[m], bh[n], acc[m][n], 0, 0, 0);
                    acc[m][n] = __builtin_amdgcn_mfma_f32_16x16x32_bf16(ah[m], bl[n], acc[m][n], 0, 0, 0);
                    acc[m][n] = __builtin_amdgcn_mfma_f32_16x16x32_bf16(al[m], bh[n], acc[m][n], 0, 0, 0);
                }
        }
        __syncthreads();
    }

    // epilogue: C/D layout col(t)=lane&15, row(e)=(lane>>4)*4+reg
    float tau = tau0[b];
    float zs = 0.f;
    int erow0 = e0 + wr * 64 + (lane >> 4) * 4;
#pragma unroll
    for (int m = 0; m < 4; ++m)
#pragma unroll
        for (int r = 0; r < 4; ++r) {
            int e = erow0 + m * 16 + r;
            float mbe = mb[e];
#pragma unroll
            for (int n = 0; n < 4; ++n) {
                int t = t0 + wc * 64 + n * 16 + a15;
                float v = acc[m][n][r] + mbe;
                zs += __expf(v);
                if (v >= tau) {
                    int pos = atomicAdd(&scnt, 1);       // LDS atomic (fast)
                    if (pos < BCAP_) {
                        sval[pos] = v;
                        sidx[pos] = e * T_ + t;
                    } else {                             // rare overflow spill
                        int q2 = atomicAdd(&ovc[b], 1);
                        if (q2 < OCAP_) {
                            ovv[b * OCAP_ + q2] = v;
                            ovi[b * OCAP_ + q2] = e * T_ + t;
                        }
                    }
                }
            }
        }
#pragma unroll
    for (int off = 32; off; off >>= 1) zs += __shfl_xor(zs, off, 64);
    if (lane == 0) red[w] = zs;
    __syncthreads();
    // flush: plain stores only
    int nc = scnt < BCAP_ ? scnt : BCAP_;
    for (int j = tid; j < nc; j += 256) {
        cvalB[(size_t)f * BCAP_ + j] = sval[j];
        cidxB[(size_t)f * BCAP_ + j] = sidx[j];
    }
    if (tid == 0) {
        cntB[f] = nc;
        zpart[f] = (red[0] + red[1]) + (red[2] + red[3]);
    }
}

// fused compact + exact top-K selection (one block per batch)
__launch_bounds__(256)
__global__ void k_selectc(const float* __restrict__ zpart, const int* __restrict__ cntB,
                          const float* __restrict__ cvalB, const int* __restrict__ cidxB,
                          const int* __restrict__ ovc, const float* __restrict__ ovv,
                          const int* __restrict__ ovi, float* __restrict__ cval,
                          int* __restrict__ cidx, int* __restrict__ sel_e,
                          int* __restrict__ sel_t, float* __restrict__ sel_sp) {
    __shared__ int pre[256];
    __shared__ float zsh[256];
    __shared__ int h[NB2_];
    __shared__ int part[256];
    __shared__ float bl_v[1024];
    __shared__ int bl_i[1024];
    __shared__ int nb, bstar, nabove, outcnt, ntot;
    int b = blockIdx.x, tid = threadIdx.x;
    // ---- compact phase ----
    int f = b + 8 * tid;                     // region id (b == f&7 decode)
    int c = cntB[f];
    pre[tid] = c;
    zsh[tid] = zpart[f];
    __syncthreads();
    for (int d = 1; d < 256; d <<= 1) {      // inclusive scan
        int v = (tid >= d) ? pre[tid - d] : 0;
        __syncthreads();
        pre[tid] += v;
        __syncthreads();
    }
    int start = pre[tid] - c;
    int total = pre[255];
    for (int j = 0; j < c; ++j) {
        int d = start + j;
        if (d < CAP_) {
            cval[b * CAP_ + d] = cvalB[(size_t)f * BCAP_ + j];
            cidx[b * CAP_ + d] = cidxB[(size_t)f * BCAP_ + j];
        }
    }
    __syncthreads();
    for (int d = 128; d; d >>= 1) {          // Z reduction
        if (tid < d) zsh[tid] += zsh[tid + d];
        __syncthreads();
    }
    int no = ovc[b]; if (no > OCAP_) no = OCAP_;
    for (int j = tid; j < no; j += 256) {
        int d = total + j;
        if (d < CAP_) {
            cval[b * CAP_ + d] = ovv[b * OCAP_ + j];
            cidx[b * CAP_ + d] = ovi[b * OCAP_ + j];
        }
    }
    if (tid == 0) {
        int tot = total + no;
        ntot = tot < CAP_ ? tot : CAP_;
        nb = 0; outcnt = 0;
    }
    for (int i = tid; i < NB2_; i += 256) h[i] = 0;
    __syncthreads();                          // drains global writes (vmcnt 0)
    // ---- select phase ----
    int n = ntot;
    float Zb = zsh[0];
    const float* vp = cval + b * CAP_;
    const int* ip = cidx + b * CAP_;
    for (int j = tid; j < n; j += 256) {
        int bin = (int)(vp[j] * ((float)NB2_ * 2.0f));   // [0,0.5) range
        bin = bin < 0 ? 0 : (bin > NB2_ - 1 ? NB2_ - 1 : bin);
        atomicAdd(&h[bin], 1);
    }
    __syncthreads();
    int ps = 0;
    for (int j = 0; j < 16; ++j) ps += h[tid * 16 + j];
    part[tid] = ps;
    __syncthreads();
    if (tid == 0) {
        int cum = 0, bs = 0, na = 0;
        for (int i = 255; i >= 0; --i) {
            if (cum + part[i] >= K_) {
                int cum2 = cum;
                for (int j = 15; j >= 0; --j) {
                    cum2 += h[i * 16 + j];
                    if (cum2 >= K_) { bs = i * 16 + j; na = cum2 - h[i * 16 + j]; break; }
                }
                break;
            }
            cum += part[i];
        }
        bstar = bs; nabove = na;
    }
    __syncthreads();
    int bs = bstar;
    for (int j = tid; j < n; j += 256) {
        float v = vp[j];
        int bin = (int)(v * ((float)NB2_ * 2.0f));
        bin = bin < 0 ? 0 : (bin > NB2_ - 1 ? NB2_ - 1 : bin);
        if (bin == bs) {
            int q = atomicAdd(&nb, 1);
            if (q < 1024) { bl_v[q] = v; bl_i[q] = ip[j]; }
        }
    }
    __syncthreads();
    float rZ = 1.0f / Zb;
    for (int j = tid; j < n; j += 256) {
        float v = vp[j];
        int bin = (int)(v * ((float)NB2_ * 2.0f));
        bin = bin < 0 ? 0 : (bin > NB2_ - 1 ? NB2_ - 1 : bin);
        if (bin > bs) {
            int q = atomicAdd(&outcnt, 1);
            int idx = ip[j];
            sel_e[b * K_ + q] = idx / T_;
            sel_t[b * K_ + q] = idx % T_;
            sel_sp[b * K_ + q] = __expf(v) * rZ;
        }
    }
    __syncthreads();
    if (tid == 0) {
        int m = nb; if (m > 1024) m = 1024;
        for (int i = 1; i < m; ++i) {          // insertion sort: val desc, idx asc
            float v = bl_v[i]; int id = bl_i[i]; int j = i - 1;
            while (j >= 0 && (bl_v[j] < v || (bl_v[j] == v && bl_i[j] > id))) {
                bl_v[j + 1] = bl_v[j]; bl_i[j + 1] = bl_i[j]; --j;
            }
            bl_v[j + 1] = v; bl_i[j + 1] = id;
        }
        int need = K_ - nabove;
        for (int q = 0; q < need; ++q) {
            int slot = nabove + q;
            if (q < m) {
                int idx = bl_i[q];
                sel_e[b * K_ + slot] = idx / T_;
                sel_t[b * K_ + slot] = idx % T_;
                sel_sp[b * K_ + slot] = __expf(bl_v[q]) * rZ;
            } else {  // pathological fallback: harmless zero entries
                sel_e[b * K_ + slot] = 0; sel_t[b * K_ + slot] = 0;
                sel_sp[b * K_ + slot] = 0.f;
            }
        }
    }
}

// up at selected positions via tiled split-x
__global__ void k_upg2(const ushort* __restrict__ xh, const ushort* __restrict__ xl,
                       const float* __restrict__ nrm, const float* __restrict__ uw,
                       const float* __restrict__ ub, const int* __restrict__ sel_e,
                       const int* __restrict__ sel_t, const float* __restrict__ sel_sp,
                       float* __restrict__ gval) {
    int gid = blockIdx.x * 256 + threadIdx.x;   // B*K waves
    int w = gid >> 6, lane = gid & 63;
    int b = w >> 9, i = w & (K_ - 1);
    int e = sel_e[b * K_ + i], t = sel_t[b * K_ + i];
    int ttile = t >> 6, trow = t & 63;
    int cc = lane >> 4, cb = (lane >> 1) & 7, half = lane & 1;
    size_t ro = ((((size_t)b * 128 + ttile) * 4 + cc) * 8 + cb) * 512
              + (size_t)trow * 8 + half * 4;          // c = lane*4 .. +4
    ushort4 h = *(const ushort4*)(xh + ro);
    ushort4 l = *(const ushort4*)(xl + ro);
    float4 wv = *(const float4*)(uw + (size_t)e * C_ + lane * 4);
    float acc = (bf2f(h.x) + bf2f(l.x)) * wv.x + (bf2f(h.y) + bf2f(l.y)) * wv.y
              + (bf2f(h.z) + bf2f(l.z)) * wv.z + (bf2f(h.w) + bf2f(l.w)) * wv.w;
#pragma unroll
    for (int off = 32; off; off >>= 1) acc += __shfl_down(acc, off, 64);
    if (lane == 0)
        gval[b * K_ + i] = sel_sp[b * K_ + i] * (acc * nrm[b * T_ + t] + ub[e]);
}

// fused base/S1/Q + BN stats: one block per channel c, 8 batches inside
__launch_bounds__(256)
__global__ void k_bsqbn(const float* __restrict__ sw, const float* __restrict__ sb,
                        const float* __restrict__ db, const float* __restrict__ dw,
                        const int* __restrict__ sel_e, const float* __restrict__ gval,
                        const float* __restrict__ bnw, const float* __restrict__ bnb,
                        float* __restrict__ scalec, float* __restrict__ obase) {
    __shared__ float barr[8], s1arr[8], qarr[8];
    int c = blockIdx.x;
    int w = threadIdx.x >> 6, lane = threadIdx.x & 63;
#pragma unroll
    for (int rep = 0; rep < 2; ++rep) {
        int b = w + rep * 4;
        float p = 0.f, s = 0.f, q = 0.f;
        for (int i = lane; i < K_; i += 64) {
            int e = sel_e[b * K_ + i];
            float g = gval[b * K_ + i];
            p += g * sw[(size_t)c * E_ + e];
            float wv = dw[(size_t)c * E_ + e] * g;
            s += wv; q += wv * wv;
        }
#pragma unroll
        for (int off = 32; off; off >>= 1) {
            p += __shfl_xor(p, off, 64);
            s += __shfl_xor(s, off, 64);
            q += __shfl_xor(q, off, 64);
        }
        if (lane == 0) {
            barr[b] = p + sb[c] + db[c];
            s1arr[b] = s; qarr[b] = q;
        }
    }
    __syncthreads();
    if (threadIdx.x == 0) {
        float msum = 0.f;
        for (int b = 0; b < B_; ++b) msum += (float)T_ * barr[b] + s1arr[b];
        float mean = msum / (float)(B_ * T_);
        float vs = 0.f;
        for (int b = 0; b < B_; ++b) {
            float d = barr[b] - mean;
            vs += (float)T_ * d * d + 2.0f * d * s1arr[b] + qarr[b];
        }
        float var = vs / (float)(B_ * T_);
        float sc = bnw[c] * rsqrtf(var + 1e-5f);
        scalec[c] = sc;
        for (int b = 0; b < B_; ++b)
            obase[b * C_ + c] = (barr[b] - mean) * sc + bnb[c];
    }
}

// fill output with column-constant base
__global__ void k_fill(const float* __restrict__ obase, float* __restrict__ out) {
    size_t gid = (size_t)blockIdx.x * 256 + threadIdx.x;
    size_t flat = gid * 4;
    int b = (int)(flat / CT_);
    int c = (int)(flat / T_) & (C_ - 1);
    float v = obase[b * C_ + c];
    float4 o = {v, v, v, v};
    *(float4*)(out + flat) = o;
}

// add spikes
__global__ void k_spikes(const float* __restrict__ dw, const float* __restrict__ scalec,
                         const int* __restrict__ sel_e, const int* __restrict__ sel_t,
                         const float* __restrict__ gval, float* __restrict__ out) {
    int gid = blockIdx.x * 256 + threadIdx.x;   // B*K*64 threads
    int s = gid >> 6, cq = (gid & 63) * 4;
    int b = s >> 9, i = s & (K_ - 1);
    int e = sel_e[b * K_ + i], t = sel_t[b * K_ + i];
    float g = gval[b * K_ + i];
#pragma unroll
    for (int q = 0; q < 4; ++q) {
        int c = cq + q;
        atomicAdd(out + (size_t)b * CT_ + (size_t)c * T_ + t,
                  scalec[c] * dw[(size_t)c * E_ + e] * g);
    }
}

extern "C" void kernel_launch(void* const* d_in, const int* in_sizes, int n_in,
                              void* d_out, int out_size, void* d_ws, size_t ws_size,
                              hipStream_t stream) {
    const float* x = (const float*)d_in[0];
    const float* up_w = (const float*)d_in[1];
    const float* up_b = (const float*)d_in[2];
    const float* mask_w = (const float*)d_in[3];
    const float* mask_b = (const float*)d_in[4];
    const float* sum_w = (const float*)d_in[5];
    const float* sum_b = (const float*)d_in[6];
    const float* down_w = (const float*)d_in[7];
    const float* down_b = (const float*)d_in[8];
    const float* bn_w = (const float*)d_in[9];
    const float* bn_b = (const float*)d_in[10];
    float* out = (float*)d_out;

    // workspace layout (float units)
    float* ws = (float*)d_ws;
    size_t o = 0;
    float* rn = ws + o;   o += (size_t)B_ * T_;
    float* nrm = ws + o;  o += (size_t)B_ * T_;
    float* xs = ws + o;   o += (size_t)B_ * C_ * SCOLS_;
    float* msub = ws + o; o += (size_t)B_ * SUBN_;
    float* tau0 = ws + o; o += B_;
    int* gh = (int*)(ws + o);    o += (size_t)B_ * NB1_;
    float* cval = ws + o; o += (size_t)B_ * CAP_;
    int* cidx = (int*)(ws + o);  o += (size_t)B_ * CAP_;
    int* sel_e = (int*)(ws + o); o += (size_t)B_ * K_;
    int* sel_t = (int*)(ws + o); o += (size_t)B_ * K_;
    float* sel_sp = ws + o; o += (size_t)B_ * K_;
    float* gval = ws + o;   o += (size_t)B_ * K_;
    float* scalec = ws + o; o += C_;
    float* obase = ws + o;  o += (size_t)B_ * C_ + 8;
    // no-atomic collection buffers
    float* zpart = ws + o;  o += NBLK_;
    int* cntB = (int*)(ws + o); o += NBLK_;
    float* cvalB = ws + o;  o += (size_t)NBLK_ * BCAP_;
    int* cidxB = (int*)(ws + o); o += (size_t)NBLK_ * BCAP_;
    int* ovc = (int*)(ws + o); o += B_;
    float* ovv = ws + o;    o += (size_t)B_ * OCAP_;
    int* ovi = (int*)(ws + o); o += (size_t)B_ * OCAP_;
    // big split buffers last
    ushort* mwh = (ushort*)(ws + o); o += (size_t)E_ * C_ / 2;
    ushort* mwl = (ushort*)(ws + o); o += (size_t)E_ * C_ / 2;
    ushort* xh = (ushort*)(ws + o);  o += (size_t)B_ * T_ * C_ / 2;
    ushort* xl = (ushort*)(ws + o);  o += (size_t)B_ * T_ * C_ / 2;
    (void)ws_size;

    k_rn<<<(B_ * T_) / 256, 256, 0, stream>>>(x, rn, nrm, ovc);
    k_gather<<<(B_ * C_ * SCOLS_) / 256, 256, 0, stream>>>(x, rn, xs, gh);
    k_msub2<<<dim3(SCOLS_ / 64, E_ / 64, B_), 256, 0, stream>>>(xs, mask_w, mask_b, msub);
    k_tau_hist<<<B_ * TAUP_, 256, 0, stream>>>(msub, gh);
    k_tau2<<<B_, 256, 0, stream>>>(gh, tau0);
    k_split_w<<<(E_ * C_ / 8) / 256, 256, 0, stream>>>(mask_w, mwh, mwl);
    k_split_x<<<dim3(T_ / 64, C_ / 64, B_), 256, 0, stream>>>(x, rn, xh, xl);
    k_gemm128<<<NBLK_, 256, 0, stream>>>(mwh, mwl, xh, xl, mask_b, tau0,
                                         zpart, cntB, cvalB, cidxB,
                                         ovc, ovv, ovi);
    k_selectc<<<B_, 256, 0, stream>>>(zpart, cntB, cvalB, cidxB,
                                      ovc, ovv, ovi, cval, cidx,
                                      sel_e, sel_t, sel_sp);
    k_upg2<<<(B_ * K_ * 64) / 256, 256, 0, stream>>>(xh, xl, nrm, up_w, up_b,
                                                     sel_e, sel_t, sel_sp, gval);
    k_bsqbn<<<C_, 256, 0, stream>>>(sum_w, sum_b, down_b, down_w, sel_e, gval,
                                    bn_w, bn_b, scalec, obase);
    k_fill<<<(B_ * CT_ / 4) / 256, 256, 0, stream>>>(obase, out);
    k_spikes<<<(B_ * K_ * 64) / 256, 256, 0, stream>>>(down_w, scalec, sel_e, sel_t,
                                                       gval, out);
}